// Round 2
// baseline (1132.651 us; speedup 1.0000x reference)
//
#include <hip/hip_runtime.h>

// GNN with hierarchical virtual nodes. All float tensors are FP32 (per the
// reference); ints are int32. Output fp32.
//
// Pipeline:
//  CSR build (hist/scan/scatter, by dst; self-loops handled implicitly)
//  GAT0: transform_in (x@w_in + scores) -> aggregate (online softmax)
//  l=0: transform_h(out + vn_emb)      -> aggregate -> VN stage (segsum+root+2xMLP)
//  l=1: transform_h(out + vn[hb])      -> aggregate -> d_out
//  (VN update after the last layer never reaches the output -> skipped)

// ---------------- CSR build ----------------
__global__ __launch_bounds__(256) void k_hist(const int* __restrict__ dst, int E,
                                              int* __restrict__ deg,
                                              const int* __restrict__ hb, int N,
                                              int* __restrict__ bins){
    int stride = gridDim.x * blockDim.x;
    for (int i = blockIdx.x*blockDim.x + threadIdx.x; i < E; i += stride)
        atomicAdd(&deg[dst[i]], 1);
    for (int i = blockIdx.x*blockDim.x + threadIdx.x; i < N; i += stride)
        atomicAdd(&bins[hb[i]], 1);
}

__global__ __launch_bounds__(256) void k_scan_a(const int* __restrict__ deg, int N,
                                                int* __restrict__ rowptr,
                                                int* __restrict__ blkSums){
    int i = blockIdx.x*256 + threadIdx.x;
    int v = (i < N) ? deg[i] : 0;
    int lane = threadIdx.x & 63, w = threadIdx.x >> 6;
    int x = v;
    #pragma unroll
    for (int o = 1; o < 64; o <<= 1){ int t = __shfl_up(x, o, 64); if (lane >= o) x += t; }
    __shared__ int ws[4];
    if (lane == 63) ws[w] = x;
    __syncthreads();
    for (int j = 0; j < w; ++j) x += ws[j];
    if (i < N) rowptr[i+1] = x;                  // block-local inclusive scan
    if (threadIdx.x == 255) blkSums[blockIdx.x] = x;
}

__global__ __launch_bounds__(1024) void k_scan_b(const int* __restrict__ blkSums, int nb,
                                                 int* __restrict__ blkOff,
                                                 const int* __restrict__ bins,
                                                 int* __restrict__ binptr,
                                                 int* __restrict__ bincur){
    __shared__ int ws[16];
    int tid = threadIdx.x;
    int lane = tid & 63, w = tid >> 6;
    // phase 1: exclusive scan of block sums (nb <= 1024)
    int v = (tid < nb) ? blkSums[tid] : 0;
    int x = v;
    #pragma unroll
    for (int o = 1; o < 64; o <<= 1){ int t = __shfl_up(x, o, 64); if (lane >= o) x += t; }
    if (lane == 63) ws[w] = x;
    __syncthreads();
    for (int j = 0; j < w; ++j) x += ws[j];
    if (tid < nb) blkOff[tid] = x - v;
    __syncthreads();
    // phase 2: exclusive scan of 256 vn-block bins
    int v2 = (tid < 256) ? bins[tid] : 0;
    int x2 = v2;
    if (tid < 256){
        #pragma unroll
        for (int o = 1; o < 64; o <<= 1){ int t = __shfl_up(x2, o, 64); if (lane >= o) x2 += t; }
        if (lane == 63) ws[w] = x2;
    }
    __syncthreads();
    if (tid < 256){
        for (int j = 0; j < w; ++j) x2 += ws[j];
        binptr[tid] = x2 - v2;
        bincur[tid] = x2 - v2;
        if (tid == 255) binptr[256] = x2;
    }
}

__global__ __launch_bounds__(256) void k_scan_c(int* __restrict__ rowptr,
                                                int* __restrict__ cursor,
                                                const int* __restrict__ blkOff, int N){
    int i = blockIdx.x*256 + threadIdx.x;
    if (i < N){
        int v = rowptr[i+1] + blkOff[blockIdx.x];
        rowptr[i+1] = v;
        if (i+1 < N) cursor[i+1] = v;
        if (i == 0){ rowptr[0] = 0; cursor[0] = 0; }
    }
}

__global__ __launch_bounds__(256) void k_scatter(const int* __restrict__ src,
                                                 const int* __restrict__ dst, int E,
                                                 int* __restrict__ cursor,
                                                 int* __restrict__ colarr,
                                                 const int* __restrict__ hb, int N,
                                                 int* __restrict__ bincur,
                                                 int* __restrict__ nodes){
    int stride = gridDim.x * blockDim.x;
    for (int i = blockIdx.x*blockDim.x + threadIdx.x; i < E; i += stride){
        int d = dst[i];
        int p = atomicAdd(&cursor[d], 1);
        colarr[p] = src[i];
    }
    for (int i = blockIdx.x*blockDim.x + threadIdx.x; i < N; i += stride){
        int b = hb[i];
        int p = atomicAdd(&bincur[b], 1);
        nodes[p] = i;
    }
}

// ---------------- dense transforms ----------------
// h = x @ W (IN=3), plus per-node attention scores s_src, s_dst
__global__ __launch_bounds__(256) void k_transform_in(const float* __restrict__ x,
                                                      const float* __restrict__ W,  // [3][64]
                                                      const float* __restrict__ a_src,
                                                      const float* __restrict__ a_dst,
                                                      float* __restrict__ hout,
                                                      float* __restrict__ ssrc,
                                                      float* __restrict__ sdst, int N){
    int wv = blockIdx.x*(blockDim.x >> 6) + (threadIdx.x >> 6);
    int lane = threadIdx.x & 63;
    if (wv >= N) return;
    float acc = 0.f;
    #pragma unroll
    for (int k = 0; k < 3; ++k)
        acc += x[wv*3 + k] * W[k*64 + lane];
    hout[(size_t)wv*64 + lane] = acc;
    float v1 = acc * a_src[lane];
    float v2 = acc * a_dst[lane];
    #pragma unroll
    for (int o = 32; o; o >>= 1){ v1 += __shfl_xor(v1, o, 64); v2 += __shfl_xor(v2, o, 64); }
    if (lane == 0){ ssrc[wv] = v1; sdst[wv] = v2; }
}

// h = (feat + vn_gather) @ W (64x64), plus scores
__global__ __launch_bounds__(256) void k_transform_h(const float* __restrict__ feat,
                                                     const float* __restrict__ vn,      // [256][64] or null
                                                     const float* __restrict__ vn_emb,  // used if vn null
                                                     const int* __restrict__ hb,
                                                     const float* __restrict__ W,       // [64][64]
                                                     const float* __restrict__ a_src,
                                                     const float* __restrict__ a_dst,
                                                     float* __restrict__ hout,
                                                     float* __restrict__ ssrc,
                                                     float* __restrict__ sdst, int N){
    __shared__ float Wl[64*64];
    for (int i = threadIdx.x; i < 64*64; i += blockDim.x) Wl[i] = W[i];
    __syncthreads();
    int wv = blockIdx.x*(blockDim.x >> 6) + (threadIdx.x >> 6);
    int lane = threadIdx.x & 63;
    if (wv >= N) return;
    float iv = feat[(size_t)wv*64 + lane];
    iv += vn ? vn[hb[wv]*64 + lane] : vn_emb[lane];
    float acc = 0.f;
    #pragma unroll
    for (int k = 0; k < 64; ++k)
        acc += __shfl(iv, k, 64) * Wl[k*64 + lane];
    hout[(size_t)wv*64 + lane] = acc;
    float v1 = acc * a_src[lane];
    float v2 = acc * a_dst[lane];
    #pragma unroll
    for (int o = 32; o; o >>= 1){ v1 += __shfl_xor(v1, o, 64); v2 += __shfl_xor(v2, o, 64); }
    if (lane == 0){ ssrc[wv] = v1; sdst[wv] = v2; }
}

// ---------------- GAT aggregation: one wave per dst, online softmax ----------------
__global__ __launch_bounds__(256) void k_aggregate(const float* __restrict__ h,
                                                   const float* __restrict__ ssrc,
                                                   const float* __restrict__ sdst,
                                                   const int* __restrict__ rowptr,
                                                   const int* __restrict__ col,
                                                   const float* __restrict__ bias,
                                                   float* __restrict__ out, int N){
    int d = blockIdx.x*(blockDim.x >> 6) + (threadIdx.x >> 6);
    int lane = threadIdx.x & 63;
    if (d >= N) return;
    float sd = sdst[d];
    // implicit self loop seeds the online softmax
    float a0 = ssrc[d] + sd; a0 = (a0 < 0.f) ? 0.2f*a0 : a0;
    float m = a0;
    float denom = 1.0f;
    float acc = h[(size_t)d*64 + lane];
    int e0 = rowptr[d], e1 = rowptr[d+1];
    for (int e = e0; e < e1; ++e){
        int s = col[e];
        float a = ssrc[s] + sd; a = (a < 0.f) ? 0.2f*a : a;
        float hv = h[(size_t)s*64 + lane];
        if (a > m){                       // wave-uniform branch
            float sc = __expf(m - a);
            denom = denom*sc + 1.0f;
            acc   = acc*sc + hv;
            m = a;
        } else {
            float wgt = __expf(a - m);
            denom += wgt;
            acc   += wgt*hv;
        }
    }
    out[(size_t)d*64 + lane] = acc/denom + bias[lane];
}

// ---------------- virtual-node stage ----------------
__global__ __launch_bounds__(64) void k_vn_segsum(const float* __restrict__ outA,
                                                  const int* __restrict__ nodes,
                                                  const int* __restrict__ binptr,
                                                  const float* __restrict__ vd_old,   // null -> vn_emb
                                                  const float* __restrict__ root_old, // null -> vn_emb
                                                  const float* __restrict__ vn_emb,
                                                  float* __restrict__ vw,             // [257][64]
                                                  float* __restrict__ colsum){        // zeroed
    int b = blockIdx.x, lane = threadIdx.x;
    float acc = 0.f;
    int i0 = binptr[b], i1 = binptr[b+1];
    for (int i = i0; i < i1; ++i){
        int n = nodes[i];
        acc += outA[(size_t)n*64 + lane];
    }
    float old  = vd_old   ? vd_old[b*64 + lane] : vn_emb[lane];
    float rold = root_old ? root_old[lane]      : vn_emb[lane];
    float v = acc + old + rold;   // vn_direct = segsum + vn_direct + vn_root
    vw[b*64 + lane] = v;
    atomicAdd(&colsum[lane], v);
}

__global__ __launch_bounds__(64) void k_vn_root(const float* __restrict__ colsum,
                                                const float* __restrict__ root_old,
                                                const float* __restrict__ vn_emb,
                                                float* __restrict__ vw){
    int lane = threadIdx.x;
    float rold = root_old ? root_old[lane] : vn_emb[lane];
    vw[256*64 + lane] = colsum[lane] + rold;   // vn_root = colsum(vn_direct) + vn_root
}

// one Linear+ReLU over 257 rows (256 vn_direct + 1 root), in place
__global__ __launch_bounds__(256) void k_vn_linear(const float* __restrict__ W,
                                                   const float* __restrict__ bias,
                                                   float* __restrict__ vw, int nrows){
    __shared__ float Wl[64*64];
    for (int i = threadIdx.x; i < 64*64; i += blockDim.x) Wl[i] = W[i];
    __syncthreads();
    int wv = blockIdx.x*(blockDim.x >> 6) + (threadIdx.x >> 6);
    int lane = threadIdx.x & 63;
    if (wv >= nrows) return;
    float iv = vw[wv*64 + lane];
    float acc = bias[lane];
    #pragma unroll
    for (int k = 0; k < 64; ++k)
        acc += __shfl(iv, k, 64) * Wl[k*64 + lane];
    vw[wv*64 + lane] = fmaxf(acc, 0.f);
}

extern "C" void kernel_launch(void* const* d_in, const int* in_sizes, int n_in,
                              void* d_out, int out_size, void* d_ws, size_t ws_size,
                              hipStream_t stream) {
    const int N = in_sizes[0] / 3;
    const int E = in_sizes[1] / 2;
    const int L = in_sizes[9] / (64*64);

    const float* x        = (const float*)d_in[0];
    const int*   edge     = (const int*)d_in[1];
    const int*   srcp     = edge;
    const int*   dstp     = edge + E;
    const int*   hb       = (const int*)d_in[2];
    // d_in[3] = h_levels (unused by reference), d_in[4] = h_num (256)
    const float* w_in     = (const float*)d_in[5];
    const float* a_src_in = (const float*)d_in[6];
    const float* a_dst_in = (const float*)d_in[7];
    const float* b_in     = (const float*)d_in[8];
    const float* w_l      = (const float*)d_in[9];
    const float* a_src_l  = (const float*)d_in[10];
    const float* a_dst_l  = (const float*)d_in[11];
    const float* b_l      = (const float*)d_in[12];
    const float* mlp_w1   = (const float*)d_in[13];
    const float* mlp_b1   = (const float*)d_in[14];
    const float* mlp_w2   = (const float*)d_in[15];
    const float* mlp_b2   = (const float*)d_in[16];
    const float* vn_emb   = (const float*)d_in[17];
    float*       out      = (float*)d_out;

    // ---- workspace carve (256B-aligned) ----
    char* ws = (char*)d_ws;
    size_t off = 0;
    auto carve = [&](size_t bytes) -> char* {
        char* p = ws + off;
        off = (off + bytes + 255) & ~(size_t)255;
        return p;
    };
    float* h      = (float*)carve((size_t)N*64*4);
    float* outA   = (float*)carve((size_t)N*64*4);
    float* ssrc   = (float*)carve((size_t)N*4);
    float* sdst   = (float*)carve((size_t)N*4);
    int*   rowptr = (int*)carve((size_t)(N+1)*4);
    int*   cursor = (int*)carve((size_t)N*4);
    char*  zstart = ws + off;
    int*   deg    = (int*)carve((size_t)N*4);
    int*   bins   = (int*)carve(256*4);
    int*   bincur = (int*)carve(256*4);
    float* colsum = (float*)carve(64*4);
    size_t zbytes = (size_t)((ws + off) - zstart);
    int*   binptr = (int*)carve(257*4);
    const int nb  = (N + 255) / 256;
    int*   blkSums= (int*)carve((size_t)nb*4);
    int*   blkOff = (int*)carve((size_t)nb*4);
    int*   colarr = (int*)carve((size_t)E*4);
    int*   nodes  = (int*)carve((size_t)N*4);
    float* vw     = (float*)carve((size_t)257*64*4);
    if (off > ws_size) return;   // workspace too small -> visible as wrong output

    // ---- CSR build ----
    hipMemsetAsync(zstart, 0, zbytes, stream);
    const int gs = 512;
    k_hist   <<<gs, 256, 0, stream>>>(dstp, E, deg, hb, N, bins);
    k_scan_a <<<nb, 256, 0, stream>>>(deg, N, rowptr, blkSums);
    k_scan_b <<<1, 1024, 0, stream>>>(blkSums, nb, blkOff, bins, binptr, bincur);
    k_scan_c <<<nb, 256, 0, stream>>>(rowptr, cursor, blkOff, N);
    k_scatter<<<gs, 256, 0, stream>>>(srcp, dstp, E, cursor, colarr, hb, N, bincur, nodes);

    const int nwb = (N + 3) / 4;   // wave-per-node kernels, 4 waves/block

    // ---- GAT layer 0 (IN -> H) ----
    k_transform_in<<<nwb, 256, 0, stream>>>(x, w_in, a_src_in, a_dst_in, h, ssrc, sdst, N);
    k_aggregate<<<nwb, 256, 0, stream>>>(h, ssrc, sdst, rowptr, colarr, b_in, outA, N);

    // ---- hidden layers ----
    for (int l = 0; l < L; ++l){
        const float* vnp = (l == 0) ? nullptr : vw;
        k_transform_h<<<nwb, 256, 0, stream>>>(outA, vnp, vn_emb, hb,
                                               w_l + (size_t)l*4096,
                                               a_src_l + (size_t)l*64,
                                               a_dst_l + (size_t)l*64,
                                               h, ssrc, sdst, N);
        const bool last = (l == L-1);
        float* dst_buf = last ? out : outA;
        k_aggregate<<<nwb, 256, 0, stream>>>(h, ssrc, sdst, rowptr, colarr,
                                             b_l + (size_t)l*64, dst_buf, N);
        if (!last){
            // VN stage (the one after the last layer is dead code -> skipped)
            hipMemsetAsync(colsum, 0, 64*4, stream);
            const float* vdo = (l == 0) ? nullptr : vw;
            const float* ro  = (l == 0) ? nullptr : (vw + 256*64);
            k_vn_segsum<<<256, 64, 0, stream>>>(outA, nodes, binptr, vdo, ro, vn_emb, vw, colsum);
            k_vn_root  <<<1, 64, 0, stream>>>(colsum, ro, vn_emb, vw);
            for (int m = 0; m < L; ++m){
                k_vn_linear<<<(257+3)/4, 256, 0, stream>>>(mlp_w1 + (size_t)m*4096,
                                                           mlp_b1 + (size_t)m*64, vw, 257);
                k_vn_linear<<<(257+3)/4, 256, 0, stream>>>(mlp_w2 + (size_t)m*4096,
                                                           mlp_b2 + (size_t)m*64, vw, 257);
            }
        }
    }
}

// Round 3
// 746.743 us; speedup vs baseline: 1.5168x; 1.5168x over previous
//
#include <hip/hip_runtime.h>

// GNN with hierarchical virtual nodes. FP32 in/out, int32 indices.
//
// Pipeline:
//  CSR build (hist/scan/scatter by dst; self-loops handled implicitly)
//  GAT0: transform_in -> aggregate (chunked parallel online softmax)
//  l=0: transform_h(out+vn_emb) -> aggregate -> VN stage (ballot-scan segsum + root + 2xMLP)
//  l=1: transform_h(out+vn[hb]) -> aggregate -> d_out
//  (VN update after the last layer never reaches the output -> skipped)

// ---------------- CSR build ----------------
__global__ __launch_bounds__(256) void k_hist(const int* __restrict__ dst, int E,
                                              int* __restrict__ deg){
    int i = blockIdx.x*256 + threadIdx.x;
    if (i < E) atomicAdd(&deg[dst[i]], 1);
}

__global__ __launch_bounds__(256) void k_scan_a(const int* __restrict__ deg, int N,
                                                int* __restrict__ rowptr,
                                                int* __restrict__ blkSums){
    int i = blockIdx.x*256 + threadIdx.x;
    int v = (i < N) ? deg[i] : 0;
    int lane = threadIdx.x & 63, w = threadIdx.x >> 6;
    int x = v;
    #pragma unroll
    for (int o = 1; o < 64; o <<= 1){ int t = __shfl_up(x, o, 64); if (lane >= o) x += t; }
    __shared__ int sums[4];
    if (lane == 63) sums[w] = x;
    __syncthreads();
    for (int j = 0; j < w; ++j) x += sums[j];
    if (i < N) rowptr[i+1] = x;                  // block-local inclusive scan
    if (threadIdx.x == 255) blkSums[blockIdx.x] = x;
}

__global__ __launch_bounds__(1024) void k_scan_b(const int* __restrict__ blkSums, int nb,
                                                 int* __restrict__ blkOff){
    __shared__ int sums[16];
    int tid = threadIdx.x;
    int lane = tid & 63, w = tid >> 6;
    int v = (tid < nb) ? blkSums[tid] : 0;
    int x = v;
    #pragma unroll
    for (int o = 1; o < 64; o <<= 1){ int t = __shfl_up(x, o, 64); if (lane >= o) x += t; }
    if (lane == 63) sums[w] = x;
    __syncthreads();
    for (int j = 0; j < w; ++j) x += sums[j];
    if (tid < nb) blkOff[tid] = x - v;           // exclusive scan of block sums
}

__global__ __launch_bounds__(256) void k_scan_c(int* __restrict__ rowptr,
                                                int* __restrict__ cursor,
                                                const int* __restrict__ blkOff, int N){
    int i = blockIdx.x*256 + threadIdx.x;
    if (i < N){
        int v = rowptr[i+1] + blkOff[blockIdx.x];
        rowptr[i+1] = v;
        if (i+1 < N) cursor[i+1] = v;
        if (i == 0){ rowptr[0] = 0; cursor[0] = 0; }
    }
}

__global__ __launch_bounds__(256) void k_scatter(const int* __restrict__ src,
                                                 const int* __restrict__ dst, int E,
                                                 int* __restrict__ cursor,
                                                 int* __restrict__ colarr){
    int i = blockIdx.x*256 + threadIdx.x;
    if (i < E){
        int p = atomicAdd(&cursor[dst[i]], 1);
        colarr[p] = src[i];
    }
}

// ---------------- dense transforms ----------------
__global__ __launch_bounds__(256) void k_transform_in(const float* __restrict__ x,
                                                      const float* __restrict__ W,  // [3][64]
                                                      const float* __restrict__ a_src,
                                                      const float* __restrict__ a_dst,
                                                      float* __restrict__ hout,
                                                      float* __restrict__ ssrc,
                                                      float* __restrict__ sdst, int N){
    int wv = blockIdx.x*4 + (threadIdx.x >> 6);
    int lane = threadIdx.x & 63;
    if (wv >= N) return;
    float acc = 0.f;
    #pragma unroll
    for (int k = 0; k < 3; ++k)
        acc += x[wv*3 + k] * W[k*64 + lane];
    hout[(size_t)wv*64 + lane] = acc;
    float v1 = acc * a_src[lane];
    float v2 = acc * a_dst[lane];
    #pragma unroll
    for (int o = 32; o; o >>= 1){ v1 += __shfl_xor(v1, o, 64); v2 += __shfl_xor(v2, o, 64); }
    if (lane == 0){ ssrc[wv] = v1; sdst[wv] = v2; }
}

__global__ __launch_bounds__(256) void k_transform_h(const float* __restrict__ feat,
                                                     const float* __restrict__ vn,      // [256][64] or null
                                                     const float* __restrict__ vn_emb,  // used if vn null
                                                     const int* __restrict__ hb,
                                                     const float* __restrict__ W,       // [64][64]
                                                     const float* __restrict__ a_src,
                                                     const float* __restrict__ a_dst,
                                                     float* __restrict__ hout,
                                                     float* __restrict__ ssrc,
                                                     float* __restrict__ sdst, int N){
    __shared__ float Wl[64*64];
    for (int i = threadIdx.x; i < 64*64; i += 256) Wl[i] = W[i];
    __syncthreads();
    int wv = blockIdx.x*4 + (threadIdx.x >> 6);
    int lane = threadIdx.x & 63;
    if (wv >= N) return;
    float iv = feat[(size_t)wv*64 + lane];
    iv += vn ? vn[hb[wv]*64 + lane] : vn_emb[lane];
    float acc = 0.f;
    #pragma unroll
    for (int k = 0; k < 64; ++k)
        acc += __shfl(iv, k, 64) * Wl[k*64 + lane];
    hout[(size_t)wv*64 + lane] = acc;
    float v1 = acc * a_src[lane];
    float v2 = acc * a_dst[lane];
    #pragma unroll
    for (int o = 32; o; o >>= 1){ v1 += __shfl_xor(v1, o, 64); v2 += __shfl_xor(v2, o, 64); }
    if (lane == 0){ ssrc[wv] = v1; sdst[wv] = v2; }
}

// ---------------- GAT aggregation ----------------
// One wave per dst node. Chunked online softmax: lanes compute 64 edge alphas
// in parallel (coalesced col load, gathered ssrc), two wave reductions, then
// an accumulation loop with independent row gathers (weights broadcast via LDS).
__global__ __launch_bounds__(256) void k_aggregate(const float* __restrict__ h,
                                                   const float* __restrict__ ssrc,
                                                   const float* __restrict__ sdst,
                                                   const int* __restrict__ rowptr,
                                                   const int* __restrict__ col,
                                                   const float* __restrict__ bias,
                                                   float* __restrict__ out, int N){
    __shared__ float2 swb[4][64];
    int wv = threadIdx.x >> 6;
    int d = blockIdx.x*4 + wv;
    int lane = threadIdx.x & 63;
    if (d >= N) return;
    float sd = sdst[d];
    // implicit self loop seeds the state
    float a0 = ssrc[d] + sd; a0 = (a0 < 0.f) ? 0.2f*a0 : a0;
    float m = a0;
    float denom = 1.0f;
    float acc = h[(size_t)d*64 + lane];
    int e0 = rowptr[d], e1 = rowptr[d+1];
    for (int base = e0; base < e1; base += 64){
        int ne = min(64, e1 - base);
        int s = 0; float a = -1e30f;
        if (lane < ne){
            s = col[base + lane];
            a = ssrc[s] + sd; a = (a < 0.f) ? 0.2f*a : a;
        }
        float cm = a;
        #pragma unroll
        for (int o = 32; o; o >>= 1) cm = fmaxf(cm, __shfl_xor(cm, o, 64));
        float nm = fmaxf(m, cm);
        float w = (lane < ne) ? __expf(a - nm) : 0.f;
        float csum = w;
        #pragma unroll
        for (int o = 32; o; o >>= 1) csum += __shfl_xor(csum, o, 64);
        float sc = __expf(m - nm);
        denom = denom*sc + csum;
        acc *= sc;
        m = nm;
        swb[wv][lane] = make_float2(w, __int_as_float(s));
        for (int j = 0; j < ne; ++j){
            float2 p = swb[wv][j];                       // LDS broadcast
            int sj = __float_as_int(p.y);
            acc += p.x * h[(size_t)sj*64 + lane];        // independent gathers
        }
    }
    out[(size_t)d*64 + lane] = acc/denom + bias[lane];
}

// ---------------- virtual-node stage ----------------
// 256 blocks; block b scans all hb (int4 + ballot) and sums matching outA rows.
__global__ __launch_bounds__(256) void k_vn_segsum(const float* __restrict__ outA,
                                                   const int* __restrict__ hb, int N,
                                                   const float* __restrict__ vd_old,   // null -> vn_emb
                                                   const float* __restrict__ root_old, // null -> vn_emb
                                                   const float* __restrict__ vn_emb,
                                                   float* __restrict__ vw,             // [257][64]
                                                   float* __restrict__ colsum){        // zeroed
    __shared__ float part[4][64];
    int b = blockIdx.x;
    int wv = threadIdx.x >> 6, lane = threadIdx.x & 63;
    int nq = N >> 2;
    int nqp = (nq + 255) & ~255;
    float acc = 0.f;
    for (int q0 = 0; q0 < nqp; q0 += 256){
        int q = q0 + threadIdx.x;
        int4 v = make_int4(-1,-1,-1,-1);
        if (q < nq) v = ((const int4*)hb)[q];
        unsigned long long m0 = __ballot(v.x == b);
        unsigned long long m1 = __ballot(v.y == b);
        unsigned long long m2 = __ballot(v.z == b);
        unsigned long long m3 = __ballot(v.w == b);
        int qbase = q - lane;   // wave-uniform
        while (m0){ int l = __ffsll(m0)-1; m0 &= m0-1; int n = (qbase+l)*4+0; acc += outA[(size_t)n*64 + lane]; }
        while (m1){ int l = __ffsll(m1)-1; m1 &= m1-1; int n = (qbase+l)*4+1; acc += outA[(size_t)n*64 + lane]; }
        while (m2){ int l = __ffsll(m2)-1; m2 &= m2-1; int n = (qbase+l)*4+2; acc += outA[(size_t)n*64 + lane]; }
        while (m3){ int l = __ffsll(m3)-1; m3 &= m3-1; int n = (qbase+l)*4+3; acc += outA[(size_t)n*64 + lane]; }
    }
    // tail nodes (N % 4), wave-uniform work
    if (wv == 0)
        for (int t = nq*4; t < N; ++t)
            if (hb[t] == b) acc += outA[(size_t)t*64 + lane];
    part[wv][lane] = acc;
    __syncthreads();
    if (wv == 0){
        float v = part[0][lane] + part[1][lane] + part[2][lane] + part[3][lane];
        float old  = vd_old   ? vd_old[b*64 + lane] : vn_emb[lane];
        float rold = root_old ? root_old[lane]      : vn_emb[lane];
        v += old + rold;     // vn_direct = segsum + vn_direct + vn_root
        vw[b*64 + lane] = v;
        atomicAdd(&colsum[lane], v);
    }
}

__global__ __launch_bounds__(64) void k_vn_root(const float* __restrict__ colsum,
                                                const float* __restrict__ root_old,
                                                const float* __restrict__ vn_emb,
                                                float* __restrict__ vw){
    int lane = threadIdx.x;
    float rold = root_old ? root_old[lane] : vn_emb[lane];
    vw[256*64 + lane] = colsum[lane] + rold;   // vn_root = colsum(vn_direct) + vn_root
}

__global__ __launch_bounds__(256) void k_vn_linear(const float* __restrict__ W,
                                                   const float* __restrict__ bias,
                                                   float* __restrict__ vw, int nrows){
    __shared__ float Wl[64*64];
    for (int i = threadIdx.x; i < 64*64; i += 256) Wl[i] = W[i];
    __syncthreads();
    int wv = blockIdx.x*4 + (threadIdx.x >> 6);
    int lane = threadIdx.x & 63;
    if (wv >= nrows) return;
    float iv = vw[wv*64 + lane];
    float acc = bias[lane];
    #pragma unroll
    for (int k = 0; k < 64; ++k)
        acc += __shfl(iv, k, 64) * Wl[k*64 + lane];
    vw[wv*64 + lane] = fmaxf(acc, 0.f);
}

extern "C" void kernel_launch(void* const* d_in, const int* in_sizes, int n_in,
                              void* d_out, int out_size, void* d_ws, size_t ws_size,
                              hipStream_t stream) {
    const int N = in_sizes[0] / 3;
    const int E = in_sizes[1] / 2;
    const int L = in_sizes[9] / (64*64);

    const float* x        = (const float*)d_in[0];
    const int*   edge     = (const int*)d_in[1];
    const int*   srcp     = edge;
    const int*   dstp     = edge + E;
    const int*   hb       = (const int*)d_in[2];
    // d_in[3] = h_levels (unused), d_in[4] = h_num (256)
    const float* w_in     = (const float*)d_in[5];
    const float* a_src_in = (const float*)d_in[6];
    const float* a_dst_in = (const float*)d_in[7];
    const float* b_in     = (const float*)d_in[8];
    const float* w_l      = (const float*)d_in[9];
    const float* a_src_l  = (const float*)d_in[10];
    const float* a_dst_l  = (const float*)d_in[11];
    const float* b_l      = (const float*)d_in[12];
    const float* mlp_w1   = (const float*)d_in[13];
    const float* mlp_b1   = (const float*)d_in[14];
    const float* mlp_w2   = (const float*)d_in[15];
    const float* mlp_b2   = (const float*)d_in[16];
    const float* vn_emb   = (const float*)d_in[17];
    float*       out      = (float*)d_out;

    // ---- workspace carve (256B-aligned) ----
    char* ws = (char*)d_ws;
    size_t off = 0;
    auto carve = [&](size_t bytes) -> char* {
        char* p = ws + off;
        off = (off + bytes + 255) & ~(size_t)255;
        return p;
    };
    float* h      = (float*)carve((size_t)N*64*4);
    float* outA   = (float*)carve((size_t)N*64*4);
    float* ssrc   = (float*)carve((size_t)N*4);
    float* sdst   = (float*)carve((size_t)N*4);
    int*   rowptr = (int*)carve((size_t)(N+1)*4);
    int*   cursor = (int*)carve((size_t)N*4);
    char*  zstart = ws + off;
    int*   deg    = (int*)carve((size_t)N*4);
    float* colsum = (float*)carve(64*4);
    size_t zbytes = (size_t)((ws + off) - zstart);
    const int nb  = (N + 255) / 256;
    int*   blkSums= (int*)carve((size_t)nb*4);
    int*   blkOff = (int*)carve((size_t)nb*4);
    int*   colarr = (int*)carve((size_t)E*4);
    float* vw     = (float*)carve((size_t)257*64*4);
    if (off > ws_size) return;

    // ---- CSR build ----
    hipMemsetAsync(zstart, 0, zbytes, stream);
    const int gsE = (E + 255) / 256;
    k_hist   <<<gsE, 256, 0, stream>>>(dstp, E, deg);
    k_scan_a <<<nb, 256, 0, stream>>>(deg, N, rowptr, blkSums);
    k_scan_b <<<1, 1024, 0, stream>>>(blkSums, nb, blkOff);
    k_scan_c <<<nb, 256, 0, stream>>>(rowptr, cursor, blkOff, N);
    k_scatter<<<gsE, 256, 0, stream>>>(srcp, dstp, E, cursor, colarr);

    const int nwb = (N + 3) / 4;   // wave-per-node kernels, 4 waves/block

    // ---- GAT layer 0 (IN -> H) ----
    k_transform_in<<<nwb, 256, 0, stream>>>(x, w_in, a_src_in, a_dst_in, h, ssrc, sdst, N);
    k_aggregate<<<nwb, 256, 0, stream>>>(h, ssrc, sdst, rowptr, colarr, b_in, outA, N);

    // ---- hidden layers ----
    for (int l = 0; l < L; ++l){
        const float* vnp = (l == 0) ? nullptr : vw;
        k_transform_h<<<nwb, 256, 0, stream>>>(outA, vnp, vn_emb, hb,
                                               w_l + (size_t)l*4096,
                                               a_src_l + (size_t)l*64,
                                               a_dst_l + (size_t)l*64,
                                               h, ssrc, sdst, N);
        const bool last = (l == L-1);
        float* dst_buf = last ? out : outA;
        k_aggregate<<<nwb, 256, 0, stream>>>(h, ssrc, sdst, rowptr, colarr,
                                             b_l + (size_t)l*64, dst_buf, N);
        if (!last){
            // VN stage (the one after the last layer is dead code -> skipped)
            const float* vdo = (l == 0) ? nullptr : vw;
            const float* ro  = (l == 0) ? nullptr : (vw + 256*64);
            k_vn_segsum<<<256, 256, 0, stream>>>(outA, hb, N, vdo, ro, vn_emb, vw, colsum);
            k_vn_root  <<<1, 64, 0, stream>>>(colsum, ro, vn_emb, vw);
            for (int m = 0; m < L; ++m){
                k_vn_linear<<<(257+3)/4, 256, 0, stream>>>(mlp_w1 + (size_t)m*4096,
                                                           mlp_b1 + (size_t)m*64, vw, 257);
                k_vn_linear<<<(257+3)/4, 256, 0, stream>>>(mlp_w2 + (size_t)m*4096,
                                                           mlp_b2 + (size_t)m*64, vw, 257);
            }
        }
    }
}

// Round 4
// 561.834 us; speedup vs baseline: 2.0160x; 1.3291x over previous
//
#include <hip/hip_runtime.h>

// GNN with hierarchical virtual nodes. FP32 in/out, int32 indices.
//
//  CSR build (hist/scan/scatter by dst; self-loops handled implicitly)
//  GAT0: transform_in -> aggregate (chunked online softmax, float4 quad gathers)
//  l=0: transform_h_mfma(out+vn_emb) -> aggregate -> VN stage
//  l=1: transform_h_mfma(out+vn[hb]) -> aggregate -> d_out
//  (VN update after the last layer never reaches the output -> skipped)
//
// transform_h uses mfma_f32_16x16x32_bf16 with split-bf16 (hi+lo) inputs:
// X@W ~= Xh@Wh + Xh@Wl + Xl@Wh  (error ~2^-17 relative, well under threshold).

typedef __attribute__((ext_vector_type(8))) short short8;
typedef __attribute__((ext_vector_type(4))) float f32x4;

__device__ __forceinline__ unsigned short f2bf(float x){      // RNE float->bf16
    unsigned u = __float_as_uint(x);
    unsigned r = (u + 0x7fffu + ((u >> 16) & 1u)) >> 16;
    return (unsigned short)r;
}
__device__ __forceinline__ float bf2f(unsigned short b){
    return __uint_as_float(((unsigned)b) << 16);
}

// ---------------- CSR build ----------------
__global__ __launch_bounds__(256) void k_hist(const int* __restrict__ dst, int E,
                                              int* __restrict__ deg){
    int i = blockIdx.x*256 + threadIdx.x;
    if (i < E) atomicAdd(&deg[dst[i]], 1);
}

__global__ __launch_bounds__(256) void k_scan_a(const int* __restrict__ deg, int N,
                                                int* __restrict__ rowptr,
                                                int* __restrict__ blkSums){
    int i = blockIdx.x*256 + threadIdx.x;
    int v = (i < N) ? deg[i] : 0;
    int lane = threadIdx.x & 63, w = threadIdx.x >> 6;
    int x = v;
    #pragma unroll
    for (int o = 1; o < 64; o <<= 1){ int t = __shfl_up(x, o, 64); if (lane >= o) x += t; }
    __shared__ int sums[4];
    if (lane == 63) sums[w] = x;
    __syncthreads();
    for (int j = 0; j < w; ++j) x += sums[j];
    if (i < N) rowptr[i+1] = x;
    if (threadIdx.x == 255) blkSums[blockIdx.x] = x;
}

__global__ __launch_bounds__(1024) void k_scan_b(const int* __restrict__ blkSums, int nb,
                                                 int* __restrict__ blkOff){
    __shared__ int sums[16];
    int tid = threadIdx.x;
    int lane = tid & 63, w = tid >> 6;
    int v = (tid < nb) ? blkSums[tid] : 0;
    int x = v;
    #pragma unroll
    for (int o = 1; o < 64; o <<= 1){ int t = __shfl_up(x, o, 64); if (lane >= o) x += t; }
    if (lane == 63) sums[w] = x;
    __syncthreads();
    for (int j = 0; j < w; ++j) x += sums[j];
    if (tid < nb) blkOff[tid] = x - v;
}

__global__ __launch_bounds__(256) void k_scan_c(int* __restrict__ rowptr,
                                                int* __restrict__ cursor,
                                                const int* __restrict__ blkOff, int N){
    int i = blockIdx.x*256 + threadIdx.x;
    if (i < N){
        int v = rowptr[i+1] + blkOff[blockIdx.x];
        rowptr[i+1] = v;
        if (i+1 < N) cursor[i+1] = v;
        if (i == 0){ rowptr[0] = 0; cursor[0] = 0; }
    }
}

__global__ __launch_bounds__(256) void k_scatter(const int* __restrict__ src,
                                                 const int* __restrict__ dst, int E,
                                                 int* __restrict__ cursor,
                                                 int* __restrict__ colarr){
    int i = blockIdx.x*256 + threadIdx.x;
    if (i < E){
        int p = atomicAdd(&cursor[dst[i]], 1);
        colarr[p] = src[i];
    }
}

// ---------------- transforms ----------------
__global__ __launch_bounds__(256) void k_transform_in(const float* __restrict__ x,
                                                      const float* __restrict__ W,  // [3][64]
                                                      const float* __restrict__ a_src,
                                                      const float* __restrict__ a_dst,
                                                      float* __restrict__ hout,
                                                      float* __restrict__ ssrc,
                                                      float* __restrict__ sdst, int N){
    int wv = blockIdx.x*4 + (threadIdx.x >> 6);
    int lane = threadIdx.x & 63;
    if (wv >= N) return;
    float acc = 0.f;
    #pragma unroll
    for (int k = 0; k < 3; ++k)
        acc += x[wv*3 + k] * W[k*64 + lane];
    hout[(size_t)wv*64 + lane] = acc;
    float v1 = acc * a_src[lane];
    float v2 = acc * a_dst[lane];
    #pragma unroll
    for (int o = 32; o; o >>= 1){ v1 += __shfl_xor(v1, o, 64); v2 += __shfl_xor(v2, o, 64); }
    if (lane == 0){ ssrc[wv] = v1; sdst[wv] = v2; }
}

// MFMA version: 64 rows per block (16 per wave), full 64 output cols per wave.
// LDS rows padded to 72 shorts: 16B-aligned b128 fragment reads, low bank aliasing.
#define LDW 72
__global__ __launch_bounds__(256) void k_transform_h_mfma(const float* __restrict__ feat,
                                                          const float* __restrict__ vn,      // [256][64] or null
                                                          const float* __restrict__ vn_emb,  // used if vn null
                                                          const int* __restrict__ hb,
                                                          const float* __restrict__ W,       // [64][64]
                                                          const float* __restrict__ a_src,
                                                          const float* __restrict__ a_dst,
                                                          float* __restrict__ hout,
                                                          float* __restrict__ ssrc,
                                                          float* __restrict__ sdst, int N){
    __shared__ unsigned short WhT[64*LDW], WlT[64*LDW], Ah[64*LDW], Al[64*LDW];
    const int n0 = blockIdx.x * 64;

    // stage W transposed, split hi/lo (reads are L2-hot; 16KB per block)
    for (int idx = threadIdx.x; idx < 4096; idx += 256){
        int n = idx >> 6, k = idx & 63;
        float w = W[k*64 + n];
        unsigned short hi = f2bf(w);
        WhT[n*LDW + k] = hi;
        WlT[n*LDW + k] = f2bf(w - bf2f(hi));
    }
    // stage A rows (feat + vn), split hi/lo
    for (int t = threadIdx.x; t < 1024; t += 256){
        int row = t >> 4, c4 = t & 15;
        int node = n0 + row;
        float4 v = make_float4(0.f,0.f,0.f,0.f);
        if (node < N){
            v = ((const float4*)feat)[(size_t)node*16 + c4];
            float4 g = vn ? ((const float4*)vn)[(size_t)hb[node]*16 + c4]
                          : ((const float4*)vn_emb)[c4];
            v.x += g.x; v.y += g.y; v.z += g.z; v.w += g.w;
        }
        int base = row*LDW + c4*4;
        unsigned short h0 = f2bf(v.x), h1 = f2bf(v.y), h2 = f2bf(v.z), h3 = f2bf(v.w);
        Ah[base+0] = h0; Al[base+0] = f2bf(v.x - bf2f(h0));
        Ah[base+1] = h1; Al[base+1] = f2bf(v.y - bf2f(h1));
        Ah[base+2] = h2; Al[base+2] = f2bf(v.z - bf2f(h2));
        Ah[base+3] = h3; Al[base+3] = f2bf(v.w - bf2f(h3));
    }
    __syncthreads();

    int lane = threadIdx.x & 63;
    int wv   = threadIdx.x >> 6;
    int mrow = lane & 15, quad = lane >> 4;
    int m0 = wv * 16;

    f32x4 acc0 = {0,0,0,0}, acc1 = {0,0,0,0}, acc2 = {0,0,0,0}, acc3 = {0,0,0,0};
    #pragma unroll
    for (int k0 = 0; k0 < 64; k0 += 32){
        int kb = k0 + quad*8;
        short8 ah = *(const short8*)&Ah[(m0+mrow)*LDW + kb];
        short8 al = *(const short8*)&Al[(m0+mrow)*LDW + kb];
        short8 b0h = *(const short8*)&WhT[( 0+mrow)*LDW + kb];
        short8 b1h = *(const short8*)&WhT[(16+mrow)*LDW + kb];
        short8 b2h = *(const short8*)&WhT[(32+mrow)*LDW + kb];
        short8 b3h = *(const short8*)&WhT[(48+mrow)*LDW + kb];
        short8 b0l = *(const short8*)&WlT[( 0+mrow)*LDW + kb];
        short8 b1l = *(const short8*)&WlT[(16+mrow)*LDW + kb];
        short8 b2l = *(const short8*)&WlT[(32+mrow)*LDW + kb];
        short8 b3l = *(const short8*)&WlT[(48+mrow)*LDW + kb];
        acc0 = __builtin_amdgcn_mfma_f32_16x16x32_bf16(ah, b0h, acc0, 0, 0, 0);
        acc1 = __builtin_amdgcn_mfma_f32_16x16x32_bf16(ah, b1h, acc1, 0, 0, 0);
        acc2 = __builtin_amdgcn_mfma_f32_16x16x32_bf16(ah, b2h, acc2, 0, 0, 0);
        acc3 = __builtin_amdgcn_mfma_f32_16x16x32_bf16(ah, b3h, acc3, 0, 0, 0);
        acc0 = __builtin_amdgcn_mfma_f32_16x16x32_bf16(ah, b0l, acc0, 0, 0, 0);
        acc1 = __builtin_amdgcn_mfma_f32_16x16x32_bf16(ah, b1l, acc1, 0, 0, 0);
        acc2 = __builtin_amdgcn_mfma_f32_16x16x32_bf16(ah, b2l, acc2, 0, 0, 0);
        acc3 = __builtin_amdgcn_mfma_f32_16x16x32_bf16(ah, b3l, acc3, 0, 0, 0);
        acc0 = __builtin_amdgcn_mfma_f32_16x16x32_bf16(al, b0h, acc0, 0, 0, 0);
        acc1 = __builtin_amdgcn_mfma_f32_16x16x32_bf16(al, b1h, acc1, 0, 0, 0);
        acc2 = __builtin_amdgcn_mfma_f32_16x16x32_bf16(al, b2h, acc2, 0, 0, 0);
        acc3 = __builtin_amdgcn_mfma_f32_16x16x32_bf16(al, b3h, acc3, 0, 0, 0);
    }

    // scores: s1[row] = sum_c out[row][c]*a_src[c]; C layout col=mrow+16t, row=quad*4+r
    float as0 = a_src[mrow], as1 = a_src[16+mrow], as2 = a_src[32+mrow], as3 = a_src[48+mrow];
    float ad0 = a_dst[mrow], ad1 = a_dst[16+mrow], ad2 = a_dst[32+mrow], ad3 = a_dst[48+mrow];
    #pragma unroll
    for (int r = 0; r < 4; ++r){
        float p1 = acc0[r]*as0 + acc1[r]*as1 + acc2[r]*as2 + acc3[r]*as3;
        float p2 = acc0[r]*ad0 + acc1[r]*ad1 + acc2[r]*ad2 + acc3[r]*ad3;
        #pragma unroll
        for (int o = 8; o; o >>= 1){ p1 += __shfl_xor(p1, o, 64); p2 += __shfl_xor(p2, o, 64); }
        int node = n0 + m0 + quad*4 + r;
        if (mrow == 0 && node < N){ ssrc[node] = p1; sdst[node] = p2; }
    }
    // write h
    #pragma unroll
    for (int r = 0; r < 4; ++r){
        int node = n0 + m0 + quad*4 + r;
        if (node < N){
            float* dst = hout + (size_t)node*64 + mrow;
            dst[ 0] = acc0[r];
            dst[16] = acc1[r];
            dst[32] = acc2[r];
            dst[48] = acc3[r];
        }
    }
}

// ---------------- GAT aggregation ----------------
// One wave per dst. Phase A: 64 edge alphas in parallel + online-softmax merge.
// Phase B: quad-parallel float4 gathers (4 source rows per instruction).
__global__ __launch_bounds__(256) void k_aggregate(const float* __restrict__ h,
                                                   const float* __restrict__ ssrc,
                                                   const float* __restrict__ sdst,
                                                   const int* __restrict__ rowptr,
                                                   const int* __restrict__ col,
                                                   const float* __restrict__ bias,
                                                   float* __restrict__ out, int N){
    __shared__ float2 swb[4][64];
    int wv = threadIdx.x >> 6;
    int d = blockIdx.x*4 + wv;
    int lane = threadIdx.x & 63;
    if (d >= N) return;
    int q = lane >> 4, c4 = lane & 15;
    const float4* h4 = (const float4*)h;
    float sd = sdst[d];
    float a0 = ssrc[d] + sd; a0 = (a0 < 0.f) ? 0.2f*a0 : a0;   // self loop seed
    float m = a0;
    float denom = 1.0f;
    float4 acc = make_float4(0.f,0.f,0.f,0.f);
    if (q == 0) acc = h4[(size_t)d*16 + c4];
    int e0 = rowptr[d], e1 = rowptr[d+1];
    for (int base = e0; base < e1; base += 64){
        int ne = min(64, e1 - base);
        int s = 0; float a = -1e30f;
        if (lane < ne){
            s = col[base + lane];
            a = ssrc[s] + sd; a = (a < 0.f) ? 0.2f*a : a;
        }
        float cm = a;
        #pragma unroll
        for (int o = 32; o; o >>= 1) cm = fmaxf(cm, __shfl_xor(cm, o, 64));
        float nm = fmaxf(m, cm);
        float w = (lane < ne) ? __expf(a - nm) : 0.f;
        float csum = w;
        #pragma unroll
        for (int o = 32; o; o >>= 1) csum += __shfl_xor(csum, o, 64);
        float sc = __expf(m - nm);
        denom = denom*sc + csum;
        acc.x *= sc; acc.y *= sc; acc.z *= sc; acc.w *= sc;
        m = nm;
        swb[wv][lane] = make_float2(w, __int_as_float(s));
        for (int j = 0; j < ne; j += 4){
            float2 p = swb[wv][j + q];                  // (w, src) for edge j+q
            int sj = __float_as_int(p.y);
            float4 hv = h4[(size_t)sj*16 + c4];
            acc.x += p.x*hv.x; acc.y += p.x*hv.y; acc.z += p.x*hv.z; acc.w += p.x*hv.w;
        }
    }
    // combine quad partials (lanes differing in bits 4,5)
    #pragma unroll
    for (int o = 16; o <= 32; o <<= 1){
        acc.x += __shfl_xor(acc.x, o, 64);
        acc.y += __shfl_xor(acc.y, o, 64);
        acc.z += __shfl_xor(acc.z, o, 64);
        acc.w += __shfl_xor(acc.w, o, 64);
    }
    if (q == 0){
        float4 b4 = ((const float4*)bias)[c4];
        float inv = 1.0f/denom;
        ((float4*)out)[(size_t)d*16 + c4] =
            make_float4(acc.x*inv + b4.x, acc.y*inv + b4.y,
                        acc.z*inv + b4.z, acc.w*inv + b4.w);
    }
}

// ---------------- virtual-node stage ----------------
__global__ __launch_bounds__(256) void k_vn_segsum(const float* __restrict__ outA,
                                                   const int* __restrict__ hb, int N,
                                                   const float* __restrict__ vd_old,
                                                   const float* __restrict__ root_old,
                                                   const float* __restrict__ vn_emb,
                                                   float* __restrict__ vw,             // [257][64]
                                                   float* __restrict__ colsum){        // zeroed
    __shared__ float part[4][64];
    int b = blockIdx.x;
    int wv = threadIdx.x >> 6, lane = threadIdx.x & 63;
    int nq = N >> 2;
    int nqp = (nq + 255) & ~255;
    float acc = 0.f;
    for (int q0 = 0; q0 < nqp; q0 += 256){
        int q = q0 + threadIdx.x;
        int4 v = make_int4(-1,-1,-1,-1);
        if (q < nq) v = ((const int4*)hb)[q];
        unsigned long long m0 = __ballot(v.x == b);
        unsigned long long m1 = __ballot(v.y == b);
        unsigned long long m2 = __ballot(v.z == b);
        unsigned long long m3 = __ballot(v.w == b);
        int qbase = q - lane;
        while (m0){ int l = __ffsll(m0)-1; m0 &= m0-1; acc += outA[(size_t)((qbase+l)*4+0)*64 + lane]; }
        while (m1){ int l = __ffsll(m1)-1; m1 &= m1-1; acc += outA[(size_t)((qbase+l)*4+1)*64 + lane]; }
        while (m2){ int l = __ffsll(m2)-1; m2 &= m2-1; acc += outA[(size_t)((qbase+l)*4+2)*64 + lane]; }
        while (m3){ int l = __ffsll(m3)-1; m3 &= m3-1; acc += outA[(size_t)((qbase+l)*4+3)*64 + lane]; }
    }
    if (wv == 0)
        for (int t = nq*4; t < N; ++t)
            if (hb[t] == b) acc += outA[(size_t)t*64 + lane];
    part[wv][lane] = acc;
    __syncthreads();
    if (wv == 0){
        float v = part[0][lane] + part[1][lane] + part[2][lane] + part[3][lane];
        float old  = vd_old   ? vd_old[b*64 + lane] : vn_emb[lane];
        float rold = root_old ? root_old[lane]      : vn_emb[lane];
        v += old + rold;
        vw[b*64 + lane] = v;
        atomicAdd(&colsum[lane], v);
    }
}

__global__ __launch_bounds__(64) void k_vn_root(const float* __restrict__ colsum,
                                                const float* __restrict__ root_old,
                                                const float* __restrict__ vn_emb,
                                                float* __restrict__ vw){
    int lane = threadIdx.x;
    float rold = root_old ? root_old[lane] : vn_emb[lane];
    vw[256*64 + lane] = colsum[lane] + rold;
}

__global__ __launch_bounds__(256) void k_vn_linear(const float* __restrict__ W,
                                                   const float* __restrict__ bias,
                                                   float* __restrict__ vw, int nrows){
    __shared__ float Wl[64*64];
    for (int i = threadIdx.x; i < 64*64; i += 256) Wl[i] = W[i];
    __syncthreads();
    int wv = blockIdx.x*4 + (threadIdx.x >> 6);
    int lane = threadIdx.x & 63;
    if (wv >= nrows) return;
    float iv = vw[wv*64 + lane];
    float acc = bias[lane];
    #pragma unroll
    for (int k = 0; k < 64; ++k)
        acc += __shfl(iv, k, 64) * Wl[k*64 + lane];
    vw[wv*64 + lane] = fmaxf(acc, 0.f);
}

extern "C" void kernel_launch(void* const* d_in, const int* in_sizes, int n_in,
                              void* d_out, int out_size, void* d_ws, size_t ws_size,
                              hipStream_t stream) {
    const int N = in_sizes[0] / 3;
    const int E = in_sizes[1] / 2;
    const int L = in_sizes[9] / (64*64);

    const float* x        = (const float*)d_in[0];
    const int*   edge     = (const int*)d_in[1];
    const int*   srcp     = edge;
    const int*   dstp     = edge + E;
    const int*   hb       = (const int*)d_in[2];
    const float* w_in     = (const float*)d_in[5];
    const float* a_src_in = (const float*)d_in[6];
    const float* a_dst_in = (const float*)d_in[7];
    const float* b_in     = (const float*)d_in[8];
    const float* w_l      = (const float*)d_in[9];
    const float* a_src_l  = (const float*)d_in[10];
    const float* a_dst_l  = (const float*)d_in[11];
    const float* b_l      = (const float*)d_in[12];
    const float* mlp_w1   = (const float*)d_in[13];
    const float* mlp_b1   = (const float*)d_in[14];
    const float* mlp_w2   = (const float*)d_in[15];
    const float* mlp_b2   = (const float*)d_in[16];
    const float* vn_emb   = (const float*)d_in[17];
    float*       out      = (float*)d_out;

    // ---- workspace carve (256B-aligned) ----
    char* ws = (char*)d_ws;
    size_t off = 0;
    auto carve = [&](size_t bytes) -> char* {
        char* p = ws + off;
        off = (off + bytes + 255) & ~(size_t)255;
        return p;
    };
    float* h      = (float*)carve((size_t)N*64*4);
    float* outA   = (float*)carve((size_t)N*64*4);
    float* ssrc   = (float*)carve((size_t)N*4);
    float* sdst   = (float*)carve((size_t)N*4);
    int*   rowptr = (int*)carve((size_t)(N+1)*4);
    int*   cursor = (int*)carve((size_t)N*4);
    char*  zstart = ws + off;
    int*   deg    = (int*)carve((size_t)N*4);
    float* colsum = (float*)carve(64*4);
    size_t zbytes = (size_t)((ws + off) - zstart);
    const int nb  = (N + 255) / 256;
    int*   blkSums= (int*)carve((size_t)nb*4);
    int*   blkOff = (int*)carve((size_t)nb*4);
    int*   colarr = (int*)carve((size_t)E*4);
    float* vw     = (float*)carve((size_t)257*64*4);
    if (off > ws_size) return;

    // ---- CSR build ----
    hipMemsetAsync(zstart, 0, zbytes, stream);
    const int gsE = (E + 255) / 256;
    k_hist   <<<gsE, 256, 0, stream>>>(dstp, E, deg);
    k_scan_a <<<nb, 256, 0, stream>>>(deg, N, rowptr, blkSums);
    k_scan_b <<<1, 1024, 0, stream>>>(blkSums, nb, blkOff);
    k_scan_c <<<nb, 256, 0, stream>>>(rowptr, cursor, blkOff, N);
    k_scatter<<<gsE, 256, 0, stream>>>(srcp, dstp, E, cursor, colarr);

    const int nwb = (N + 3) / 4;     // wave-per-node kernels
    const int nmb = (N + 63) / 64;   // mfma transform blocks

    // ---- GAT layer 0 (IN -> H) ----
    k_transform_in<<<nwb, 256, 0, stream>>>(x, w_in, a_src_in, a_dst_in, h, ssrc, sdst, N);
    k_aggregate<<<nwb, 256, 0, stream>>>(h, ssrc, sdst, rowptr, colarr, b_in, outA, N);

    // ---- hidden layers ----
    for (int l = 0; l < L; ++l){
        const float* vnp = (l == 0) ? nullptr : vw;
        k_transform_h_mfma<<<nmb, 256, 0, stream>>>(outA, vnp, vn_emb, hb,
                                                    w_l + (size_t)l*4096,
                                                    a_src_l + (size_t)l*64,
                                                    a_dst_l + (size_t)l*64,
                                                    h, ssrc, sdst, N);
        const bool last = (l == L-1);
        float* dst_buf = last ? out : outA;
        k_aggregate<<<nwb, 256, 0, stream>>>(h, ssrc, sdst, rowptr, colarr,
                                             b_l + (size_t)l*64, dst_buf, N);
        if (!last){
            const float* vdo = (l == 0) ? nullptr : vw;
            const float* ro  = (l == 0) ? nullptr : (vw + 256*64);
            k_vn_segsum<<<256, 256, 0, stream>>>(outA, hb, N, vdo, ro, vn_emb, vw, colsum);
            k_vn_root  <<<1, 64, 0, stream>>>(colsum, ro, vn_emb, vw);
            for (int m = 0; m < L; ++m){
                k_vn_linear<<<(257+3)/4, 256, 0, stream>>>(mlp_w1 + (size_t)m*4096,
                                                           mlp_b1 + (size_t)m*64, vw, 257);
                k_vn_linear<<<(257+3)/4, 256, 0, stream>>>(mlp_w2 + (size_t)m*4096,
                                                           mlp_b2 + (size_t)m*64, vw, 257);
            }
        }
    }
}

// Round 5
// 456.692 us; speedup vs baseline: 2.4801x; 1.2302x over previous
//
#include <hip/hip_runtime.h>

// GNN with hierarchical virtual nodes. FP32 in/out, int32 indices.
//
//  CSR build: bucketed (dst>>9) two-level sort -> per-bucket-owned colarr
//  regions (kills the 64B-line write amplification of random scatter).
//  GAT0: transform_in -> aggregate (chunked online softmax, float4 quad gathers)
//  l=0: transform_h_mfma(out+vn_emb) -> aggregate -> segsum -> fused VN MLP
//  l=1: transform_h_mfma(out+vn[hb]) -> aggregate -> d_out
//  (VN update after the last layer never reaches the output -> skipped)

typedef __attribute__((ext_vector_type(8))) short short8;
typedef __attribute__((ext_vector_type(4))) float f32x4;

__device__ __forceinline__ unsigned short f2bf(float x){      // RNE float->bf16
    unsigned u = __float_as_uint(x);
    unsigned r = (u + 0x7fffu + ((u >> 16) & 1u)) >> 16;
    return (unsigned short)r;
}
__device__ __forceinline__ float bf2f(unsigned short b){
    return __uint_as_float(((unsigned)b) << 16);
}

#define BSHIFT 9
#define CHUNK 4096

// inclusive scan of v across the 256 threads of the block (4 waves)
__device__ __forceinline__ int incl_scan256(int v, int* sums4){
    int lane = threadIdx.x & 63, w = threadIdx.x >> 6;
    int x = v;
    #pragma unroll
    for (int o = 1; o < 64; o <<= 1){ int t = __shfl_up(x, o, 64); if (lane >= o) x += t; }
    __syncthreads();                 // protect sums4 reuse across calls
    if (lane == 63) sums4[w] = x;
    __syncthreads();
    for (int j = 0; j < w; ++j) x += sums4[j];
    return x;
}

// ---------------- bucketed CSR build ----------------
__global__ __launch_bounds__(256) void k_bucket_count(const int* __restrict__ dst, int E, int NB,
                                                      int* __restrict__ bucketCount){
    __shared__ int cnt[256];
    cnt[threadIdx.x] = 0;
    __syncthreads();
    int base = blockIdx.x*CHUNK;
    int lim = min(base + CHUNK, E);
    for (int i = base + threadIdx.x; i < lim; i += 256)
        atomicAdd(&cnt[dst[i] >> BSHIFT], 1);
    __syncthreads();
    if (threadIdx.x < NB && cnt[threadIdx.x])
        atomicAdd(&bucketCount[threadIdx.x], cnt[threadIdx.x]);
}

__global__ __launch_bounds__(256) void k_bucket_scan(const int* __restrict__ bucketCount,
                                                     int NB, int E, int N,
                                                     int* __restrict__ bucketOff,
                                                     int* __restrict__ bucketCur,
                                                     int* __restrict__ rowptr){
    __shared__ int sums4[4];
    int v = (threadIdx.x < NB) ? bucketCount[threadIdx.x] : 0;
    int x = incl_scan256(v, sums4);
    if (threadIdx.x < NB){
        bucketOff[threadIdx.x] = x - v;
        bucketCur[threadIdx.x] = x - v;
    }
    if (threadIdx.x == NB-1) bucketOff[NB] = x;    // == E
    if (threadIdx.x == 0) rowptr[N] = E;
}

// bin (src,dst) pairs into buckets; LDS-staged so global writes are chunked/coalesced
__global__ __launch_bounds__(256) void k_bucket_place(const int* __restrict__ src,
                                                      const int* __restrict__ dst, int E, int NB,
                                                      int* __restrict__ bucketCur,
                                                      int2* __restrict__ pairs){
    __shared__ int cnt[256], binStart[256], binCur[256], chunkBase[256];
    __shared__ int sums4[4];
    __shared__ int2 lp[CHUNK];
    int tid = threadIdx.x;
    cnt[tid] = 0; binCur[tid] = 0;
    __syncthreads();
    int base = blockIdx.x*CHUNK;
    int s[16], d[16];
    #pragma unroll
    for (int k = 0; k < 16; ++k){
        int i = base + k*256 + tid;
        if (i < E){ s[k] = src[i]; d[k] = dst[i]; atomicAdd(&cnt[d[k] >> BSHIFT], 1); }
        else d[k] = -1;
    }
    __syncthreads();
    int v = cnt[tid];
    int x = incl_scan256(v, sums4);
    binStart[tid] = x - v;
    __syncthreads();
    #pragma unroll
    for (int k = 0; k < 16; ++k){
        if (d[k] >= 0){
            int b = d[k] >> BSHIFT;
            int p = binStart[b] + atomicAdd(&binCur[b], 1);
            lp[p] = make_int2(s[k], d[k]);
        }
    }
    if (tid < NB){
        int c = cnt[tid];
        chunkBase[tid] = c ? atomicAdd(&bucketCur[tid], c) : 0;
    }
    __syncthreads();
    int total = min(CHUNK, E - base);
    for (int i = tid; i < total; i += 256){
        int2 p = lp[i];
        int b = p.y >> BSHIFT;
        pairs[chunkBase[b] + (i - binStart[b])] = p;
    }
}

// one block per bucket: local deg/prefix -> rowptr segment + colarr (block-owned region)
__global__ __launch_bounds__(256) void k_bucket_csr(const int2* __restrict__ pairs,
                                                    const int* __restrict__ bucketOff, int N,
                                                    int* __restrict__ rowptr,
                                                    int* __restrict__ colarr){
    __shared__ int deg[512], cur[512];
    __shared__ int sums4[4];
    __shared__ int tAs;
    int b = blockIdx.x, tid = threadIdx.x;
    int d0 = b << BSHIFT;
    int e0 = bucketOff[b], e1 = bucketOff[b+1];
    deg[tid] = 0; deg[256+tid] = 0;
    __syncthreads();
    for (int i = e0 + tid; i < e1; i += 256)
        atomicAdd(&deg[pairs[i].y - d0], 1);
    __syncthreads();
    int vA = deg[tid], vB = deg[256+tid];
    int xA = incl_scan256(vA, sums4);
    if (tid == 255) tAs = xA;
    int xB = incl_scan256(vB, sums4) + tAs;
    int exclA = xA - vA, exclB = xB - vB;
    cur[tid] = exclA; cur[256+tid] = exclB;
    int dA = d0 + tid, dB = d0 + 256 + tid;
    if (dA < N) rowptr[dA] = e0 + exclA;
    if (dB < N) rowptr[dB] = e0 + exclB;
    __syncthreads();
    for (int i = e0 + tid; i < e1; i += 256){
        int2 p = pairs[i];
        int pos = e0 + atomicAdd(&cur[p.y - d0], 1);
        colarr[pos] = p.x;
    }
}

// ---------------- transforms ----------------
__global__ __launch_bounds__(256) void k_transform_in(const float* __restrict__ x,
                                                      const float* __restrict__ W,  // [3][64]
                                                      const float* __restrict__ a_src,
                                                      const float* __restrict__ a_dst,
                                                      float* __restrict__ hout,
                                                      float* __restrict__ ssrc,
                                                      float* __restrict__ sdst, int N){
    int wv = blockIdx.x*4 + (threadIdx.x >> 6);
    int lane = threadIdx.x & 63;
    if (wv >= N) return;
    float acc = 0.f;
    #pragma unroll
    for (int k = 0; k < 3; ++k)
        acc += x[wv*3 + k] * W[k*64 + lane];
    hout[(size_t)wv*64 + lane] = acc;
    float v1 = acc * a_src[lane];
    float v2 = acc * a_dst[lane];
    #pragma unroll
    for (int o = 32; o; o >>= 1){ v1 += __shfl_xor(v1, o, 64); v2 += __shfl_xor(v2, o, 64); }
    if (lane == 0){ ssrc[wv] = v1; sdst[wv] = v2; }
}

// MFMA transform: 64 rows/block; split-bf16 X@W ~= Xh@Wh + Xh@Wl + Xl@Wh
#define LDW 72
__global__ __launch_bounds__(256) void k_transform_h_mfma(const float* __restrict__ feat,
                                                          const float* __restrict__ vn,      // [256][64] or null
                                                          const float* __restrict__ vn_emb,  // used if vn null
                                                          const int* __restrict__ hb,
                                                          const float* __restrict__ W,       // [64][64]
                                                          const float* __restrict__ a_src,
                                                          const float* __restrict__ a_dst,
                                                          float* __restrict__ hout,
                                                          float* __restrict__ ssrc,
                                                          float* __restrict__ sdst, int N){
    __shared__ unsigned short WhT[64*LDW], WlT[64*LDW], Ah[64*LDW], Al[64*LDW];
    const int n0 = blockIdx.x * 64;

    for (int idx = threadIdx.x; idx < 4096; idx += 256){
        int n = idx >> 6, k = idx & 63;
        float w = W[k*64 + n];
        unsigned short hi = f2bf(w);
        WhT[n*LDW + k] = hi;
        WlT[n*LDW + k] = f2bf(w - bf2f(hi));
    }
    for (int t = threadIdx.x; t < 1024; t += 256){
        int row = t >> 4, c4 = t & 15;
        int node = n0 + row;
        float4 v = make_float4(0.f,0.f,0.f,0.f);
        if (node < N){
            v = ((const float4*)feat)[(size_t)node*16 + c4];
            float4 g = vn ? ((const float4*)vn)[(size_t)hb[node]*16 + c4]
                          : ((const float4*)vn_emb)[c4];
            v.x += g.x; v.y += g.y; v.z += g.z; v.w += g.w;
        }
        int base = row*LDW + c4*4;
        unsigned short h0 = f2bf(v.x), h1 = f2bf(v.y), h2 = f2bf(v.z), h3 = f2bf(v.w);
        Ah[base+0] = h0; Al[base+0] = f2bf(v.x - bf2f(h0));
        Ah[base+1] = h1; Al[base+1] = f2bf(v.y - bf2f(h1));
        Ah[base+2] = h2; Al[base+2] = f2bf(v.z - bf2f(h2));
        Ah[base+3] = h3; Al[base+3] = f2bf(v.w - bf2f(h3));
    }
    __syncthreads();

    int lane = threadIdx.x & 63;
    int wv   = threadIdx.x >> 6;
    int mrow = lane & 15, quad = lane >> 4;
    int m0 = wv * 16;

    f32x4 acc0 = {0,0,0,0}, acc1 = {0,0,0,0}, acc2 = {0,0,0,0}, acc3 = {0,0,0,0};
    #pragma unroll
    for (int k0 = 0; k0 < 64; k0 += 32){
        int kb = k0 + quad*8;
        short8 ah = *(const short8*)&Ah[(m0+mrow)*LDW + kb];
        short8 al = *(const short8*)&Al[(m0+mrow)*LDW + kb];
        short8 b0h = *(const short8*)&WhT[( 0+mrow)*LDW + kb];
        short8 b1h = *(const short8*)&WhT[(16+mrow)*LDW + kb];
        short8 b2h = *(const short8*)&WhT[(32+mrow)*LDW + kb];
        short8 b3h = *(const short8*)&WhT[(48+mrow)*LDW + kb];
        short8 b0l = *(const short8*)&WlT[( 0+mrow)*LDW + kb];
        short8 b1l = *(const short8*)&WlT[(16+mrow)*LDW + kb];
        short8 b2l = *(const short8*)&WlT[(32+mrow)*LDW + kb];
        short8 b3l = *(const short8*)&WlT[(48+mrow)*LDW + kb];
        acc0 = __builtin_amdgcn_mfma_f32_16x16x32_bf16(ah, b0h, acc0, 0, 0, 0);
        acc1 = __builtin_amdgcn_mfma_f32_16x16x32_bf16(ah, b1h, acc1, 0, 0, 0);
        acc2 = __builtin_amdgcn_mfma_f32_16x16x32_bf16(ah, b2h, acc2, 0, 0, 0);
        acc3 = __builtin_amdgcn_mfma_f32_16x16x32_bf16(ah, b3h, acc3, 0, 0, 0);
        acc0 = __builtin_amdgcn_mfma_f32_16x16x32_bf16(ah, b0l, acc0, 0, 0, 0);
        acc1 = __builtin_amdgcn_mfma_f32_16x16x32_bf16(ah, b1l, acc1, 0, 0, 0);
        acc2 = __builtin_amdgcn_mfma_f32_16x16x32_bf16(ah, b2l, acc2, 0, 0, 0);
        acc3 = __builtin_amdgcn_mfma_f32_16x16x32_bf16(ah, b3l, acc3, 0, 0, 0);
        acc0 = __builtin_amdgcn_mfma_f32_16x16x32_bf16(al, b0h, acc0, 0, 0, 0);
        acc1 = __builtin_amdgcn_mfma_f32_16x16x32_bf16(al, b1h, acc1, 0, 0, 0);
        acc2 = __builtin_amdgcn_mfma_f32_16x16x32_bf16(al, b2h, acc2, 0, 0, 0);
        acc3 = __builtin_amdgcn_mfma_f32_16x16x32_bf16(al, b3h, acc3, 0, 0, 0);
    }

    float as0 = a_src[mrow], as1 = a_src[16+mrow], as2 = a_src[32+mrow], as3 = a_src[48+mrow];
    float ad0 = a_dst[mrow], ad1 = a_dst[16+mrow], ad2 = a_dst[32+mrow], ad3 = a_dst[48+mrow];
    #pragma unroll
    for (int r = 0; r < 4; ++r){
        float p1 = acc0[r]*as0 + acc1[r]*as1 + acc2[r]*as2 + acc3[r]*as3;
        float p2 = acc0[r]*ad0 + acc1[r]*ad1 + acc2[r]*ad2 + acc3[r]*ad3;
        #pragma unroll
        for (int o = 8; o; o >>= 1){ p1 += __shfl_xor(p1, o, 64); p2 += __shfl_xor(p2, o, 64); }
        int node = n0 + m0 + quad*4 + r;
        if (mrow == 0 && node < N){ ssrc[node] = p1; sdst[node] = p2; }
    }
    #pragma unroll
    for (int r = 0; r < 4; ++r){
        int node = n0 + m0 + quad*4 + r;
        if (node < N){
            float* dst = hout + (size_t)node*64 + mrow;
            dst[ 0] = acc0[r];
            dst[16] = acc1[r];
            dst[32] = acc2[r];
            dst[48] = acc3[r];
        }
    }
}

// ---------------- GAT aggregation ----------------
__global__ __launch_bounds__(256) void k_aggregate(const float* __restrict__ h,
                                                   const float* __restrict__ ssrc,
                                                   const float* __restrict__ sdst,
                                                   const int* __restrict__ rowptr,
                                                   const int* __restrict__ col,
                                                   const float* __restrict__ bias,
                                                   float* __restrict__ out, int N){
    __shared__ float2 swb[4][64];
    int wv = threadIdx.x >> 6;
    int d = blockIdx.x*4 + wv;
    int lane = threadIdx.x & 63;
    if (d >= N) return;
    int q = lane >> 4, c4 = lane & 15;
    const float4* h4 = (const float4*)h;
    float sd = sdst[d];
    float a0 = ssrc[d] + sd; a0 = (a0 < 0.f) ? 0.2f*a0 : a0;   // self loop seed
    float m = a0;
    float denom = 1.0f;
    float4 acc = make_float4(0.f,0.f,0.f,0.f);
    if (q == 0) acc = h4[(size_t)d*16 + c4];
    int e0 = rowptr[d], e1 = rowptr[d+1];
    for (int base = e0; base < e1; base += 64){
        int ne = min(64, e1 - base);
        int s = 0; float a = -1e30f;
        if (lane < ne){
            s = col[base + lane];
            a = ssrc[s] + sd; a = (a < 0.f) ? 0.2f*a : a;
        }
        float cm = a;
        #pragma unroll
        for (int o = 32; o; o >>= 1) cm = fmaxf(cm, __shfl_xor(cm, o, 64));
        float nm = fmaxf(m, cm);
        float w = (lane < ne) ? __expf(a - nm) : 0.f;
        float csum = w;
        #pragma unroll
        for (int o = 32; o; o >>= 1) csum += __shfl_xor(csum, o, 64);
        float sc = __expf(m - nm);
        denom = denom*sc + csum;
        acc.x *= sc; acc.y *= sc; acc.z *= sc; acc.w *= sc;
        m = nm;
        swb[wv][lane] = make_float2(w, __int_as_float(s));
        for (int j = 0; j < ne; j += 4){
            float2 p = swb[wv][j + q];
            int sj = __float_as_int(p.y);
            float4 hv = h4[(size_t)sj*16 + c4];
            acc.x += p.x*hv.x; acc.y += p.x*hv.y; acc.z += p.x*hv.z; acc.w += p.x*hv.w;
        }
    }
    #pragma unroll
    for (int o = 16; o <= 32; o <<= 1){
        acc.x += __shfl_xor(acc.x, o, 64);
        acc.y += __shfl_xor(acc.y, o, 64);
        acc.z += __shfl_xor(acc.z, o, 64);
        acc.w += __shfl_xor(acc.w, o, 64);
    }
    if (q == 0){
        float4 b4 = ((const float4*)bias)[c4];
        float inv = 1.0f/denom;
        ((float4*)out)[(size_t)d*16 + c4] =
            make_float4(acc.x*inv + b4.x, acc.y*inv + b4.y,
                        acc.z*inv + b4.z, acc.w*inv + b4.w);
    }
}

// ---------------- virtual-node stage ----------------
__global__ __launch_bounds__(256) void k_vn_segsum(const float* __restrict__ outA,
                                                   const int* __restrict__ hb, int N,
                                                   const float* __restrict__ vd_old,
                                                   const float* __restrict__ root_old,
                                                   const float* __restrict__ vn_emb,
                                                   float* __restrict__ vw,             // [257][64]
                                                   float* __restrict__ colsum){        // zeroed
    __shared__ float part[4][64];
    int b = blockIdx.x;
    int wv = threadIdx.x >> 6, lane = threadIdx.x & 63;
    int nq = N >> 2;
    int nqp = (nq + 255) & ~255;
    float acc = 0.f;
    for (int q0 = 0; q0 < nqp; q0 += 256){
        int q = q0 + threadIdx.x;
        int4 v = make_int4(-1,-1,-1,-1);
        if (q < nq) v = ((const int4*)hb)[q];
        unsigned long long m0 = __ballot(v.x == b);
        unsigned long long m1 = __ballot(v.y == b);
        unsigned long long m2 = __ballot(v.z == b);
        unsigned long long m3 = __ballot(v.w == b);
        int qbase = q - lane;
        while (m0){ int l = __ffsll(m0)-1; m0 &= m0-1; acc += outA[(size_t)((qbase+l)*4+0)*64 + lane]; }
        while (m1){ int l = __ffsll(m1)-1; m1 &= m1-1; acc += outA[(size_t)((qbase+l)*4+1)*64 + lane]; }
        while (m2){ int l = __ffsll(m2)-1; m2 &= m2-1; acc += outA[(size_t)((qbase+l)*4+2)*64 + lane]; }
        while (m3){ int l = __ffsll(m3)-1; m3 &= m3-1; acc += outA[(size_t)((qbase+l)*4+3)*64 + lane]; }
    }
    if (wv == 0)
        for (int t = nq*4; t < N; ++t)
            if (hb[t] == b) acc += outA[(size_t)t*64 + lane];
    part[wv][lane] = acc;
    __syncthreads();
    if (wv == 0){
        float v = part[0][lane] + part[1][lane] + part[2][lane] + part[3][lane];
        float old  = vd_old   ? vd_old[b*64 + lane] : vn_emb[lane];
        float rold = root_old ? root_old[lane]      : vn_emb[lane];
        v += old + rold;
        vw[b*64 + lane] = v;
        atomicAdd(&colsum[lane], v);
    }
}

// fused: root assembly + L x (Linear-ReLU-Linear-ReLU) over 257 independent rows
__global__ __launch_bounds__(256) void k_vn_mlp(const float* __restrict__ colsum,
                                                const float* __restrict__ root_old,
                                                const float* __restrict__ vn_emb,
                                                const float* __restrict__ mlp_w1,
                                                const float* __restrict__ mlp_b1,
                                                const float* __restrict__ mlp_w2,
                                                const float* __restrict__ mlp_b2,
                                                int L, float* __restrict__ vw){
    __shared__ float Wl[64*64];
    int wv = blockIdx.x*4 + (threadIdx.x >> 6);
    int lane = threadIdx.x & 63;
    bool valid = (wv < 257);
    float iv = 0.f;
    if (valid){
        if (wv == 256){
            float rold = root_old ? root_old[lane] : vn_emb[lane];
            iv = colsum[lane] + rold;            // vn_root = colsum + vn_root_old
        } else {
            iv = vw[wv*64 + lane];
        }
    }
    for (int m = 0; m < L; ++m){
        #pragma unroll
        for (int half = 0; half < 2; ++half){
            const float* W    = (half ? mlp_w2 : mlp_w1) + (size_t)m*4096;
            const float* bias = (half ? mlp_b2 : mlp_b1) + (size_t)m*64;
            __syncthreads();
            for (int i = threadIdx.x; i < 4096; i += 256) Wl[i] = W[i];
            __syncthreads();
            float acc = bias[lane];
            #pragma unroll
            for (int k = 0; k < 64; ++k)
                acc += __shfl(iv, k, 64) * Wl[k*64 + lane];
            iv = fmaxf(acc, 0.f);
        }
    }
    if (valid) vw[wv*64 + lane] = iv;
}

extern "C" void kernel_launch(void* const* d_in, const int* in_sizes, int n_in,
                              void* d_out, int out_size, void* d_ws, size_t ws_size,
                              hipStream_t stream) {
    const int N = in_sizes[0] / 3;
    const int E = in_sizes[1] / 2;
    const int L = in_sizes[9] / (64*64);
    const int NB = (N + (1<<BSHIFT) - 1) >> BSHIFT;   // buckets (<=256 for N<=131072)

    const float* x        = (const float*)d_in[0];
    const int*   edge     = (const int*)d_in[1];
    const int*   srcp     = edge;
    const int*   dstp     = edge + E;
    const int*   hb       = (const int*)d_in[2];
    const float* w_in     = (const float*)d_in[5];
    const float* a_src_in = (const float*)d_in[6];
    const float* a_dst_in = (const float*)d_in[7];
    const float* b_in     = (const float*)d_in[8];
    const float* w_l      = (const float*)d_in[9];
    const float* a_src_l  = (const float*)d_in[10];
    const float* a_dst_l  = (const float*)d_in[11];
    const float* b_l      = (const float*)d_in[12];
    const float* mlp_w1   = (const float*)d_in[13];
    const float* mlp_b1   = (const float*)d_in[14];
    const float* mlp_w2   = (const float*)d_in[15];
    const float* mlp_b2   = (const float*)d_in[16];
    const float* vn_emb   = (const float*)d_in[17];
    float*       out      = (float*)d_out;

    // ---- workspace carve (256B-aligned) ----
    char* ws = (char*)d_ws;
    size_t off = 0;
    auto carve = [&](size_t bytes) -> char* {
        char* p = ws + off;
        off = (off + bytes + 255) & ~(size_t)255;
        return p;
    };
    float* h      = (float*)carve((size_t)N*64*4);   // also aliased as pairs during CSR build
    float* outA   = (float*)carve((size_t)N*64*4);
    float* ssrc   = (float*)carve((size_t)N*4);
    float* sdst   = (float*)carve((size_t)N*4);
    int*   rowptr = (int*)carve((size_t)(N+1)*4);
    char*  zstart = ws + off;
    int*   bucketCount = (int*)carve(256*4);
    float* colsum = (float*)carve(64*4);
    size_t zbytes = (size_t)((ws + off) - zstart);
    int*   bucketOff = (int*)carve(257*4);
    int*   bucketCur = (int*)carve(256*4);
    int*   colarr = (int*)carve((size_t)E*4);
    float* vw     = (float*)carve((size_t)257*64*4);
    if (off > ws_size) return;
    int2* pairs = (int2*)h;   // pairs dead before h's first write

    // ---- CSR build (bucketed) ----
    hipMemsetAsync(zstart, 0, zbytes, stream);
    const int nchunk = (E + CHUNK - 1) / CHUNK;
    k_bucket_count<<<nchunk, 256, 0, stream>>>(dstp, E, NB, bucketCount);
    k_bucket_scan <<<1, 256, 0, stream>>>(bucketCount, NB, E, N, bucketOff, bucketCur, rowptr);
    k_bucket_place<<<nchunk, 256, 0, stream>>>(srcp, dstp, E, NB, bucketCur, pairs);
    k_bucket_csr  <<<NB, 256, 0, stream>>>(pairs, bucketOff, N, rowptr, colarr);

    const int nwb = (N + 3) / 4;     // wave-per-node kernels
    const int nmb = (N + 63) / 64;   // mfma transform blocks

    // ---- GAT layer 0 (IN -> H) ----
    k_transform_in<<<nwb, 256, 0, stream>>>(x, w_in, a_src_in, a_dst_in, h, ssrc, sdst, N);
    k_aggregate<<<nwb, 256, 0, stream>>>(h, ssrc, sdst, rowptr, colarr, b_in, outA, N);

    // ---- hidden layers ----
    for (int l = 0; l < L; ++l){
        const float* vnp = (l == 0) ? nullptr : vw;
        k_transform_h_mfma<<<nmb, 256, 0, stream>>>(outA, vnp, vn_emb, hb,
                                                    w_l + (size_t)l*4096,
                                                    a_src_l + (size_t)l*64,
                                                    a_dst_l + (size_t)l*64,
                                                    h, ssrc, sdst, N);
        const bool last = (l == L-1);
        float* dst_buf = last ? out : outA;
        k_aggregate<<<nwb, 256, 0, stream>>>(h, ssrc, sdst, rowptr, colarr,
                                             b_l + (size_t)l*64, dst_buf, N);
        if (!last){
            const float* vdo = (l == 0) ? nullptr : vw;
            const float* ro  = (l == 0) ? nullptr : (vw + 256*64);
            k_vn_segsum<<<256, 256, 0, stream>>>(outA, hb, N, vdo, ro, vn_emb, vw, colsum);
            k_vn_mlp<<<(257+3)/4, 256, 0, stream>>>(colsum, ro, vn_emb,
                                                    mlp_w1, mlp_b1, mlp_w2, mlp_b2, L, vw);
        }
    }
}

// Round 6
// 440.980 us; speedup vs baseline: 2.5685x; 1.0356x over previous
//
#include <hip/hip_runtime.h>

// GNN with hierarchical virtual nodes. FP32 in/out, int32 indices.
//
//  CSR build: bucketed (dst>>9) two-level sort -> per-bucket-owned colarr
//  regions (kills the 64B-line write amplification of random scatter).
//  h (per-layer transformed features) stored as BF16: halves the random-gather
//  traffic in aggregate (the dominant cost); scores stay fp32.
//  GAT0: transform_in -> aggregate (chunked online softmax, uint2 bf16 gathers)
//  l=0: transform_h_mfma(out+vn_emb) -> aggregate -> segsum -> fused VN MLP
//  l=1: transform_h_mfma(out+vn[hb]) -> aggregate -> d_out
//  (VN update after the last layer never reaches the output -> skipped)

typedef __attribute__((ext_vector_type(8))) short short8;
typedef __attribute__((ext_vector_type(4))) float f32x4;

__device__ __forceinline__ unsigned short f2bf(float x){      // RNE float->bf16
    unsigned u = __float_as_uint(x);
    unsigned r = (u + 0x7fffu + ((u >> 16) & 1u)) >> 16;
    return (unsigned short)r;
}
__device__ __forceinline__ float bf2f(unsigned short b){
    return __uint_as_float(((unsigned)b) << 16);
}

#define BSHIFT 9
#define CHUNK 4096

// inclusive scan of v across the 256 threads of the block (4 waves)
__device__ __forceinline__ int incl_scan256(int v, int* sums4){
    int lane = threadIdx.x & 63, w = threadIdx.x >> 6;
    int x = v;
    #pragma unroll
    for (int o = 1; o < 64; o <<= 1){ int t = __shfl_up(x, o, 64); if (lane >= o) x += t; }
    __syncthreads();                 // protect sums4 reuse across calls
    if (lane == 63) sums4[w] = x;
    __syncthreads();
    for (int j = 0; j < w; ++j) x += sums4[j];
    return x;
}

// ---------------- bucketed CSR build ----------------
__global__ __launch_bounds__(256) void k_bucket_count(const int* __restrict__ dst, int E, int NB,
                                                      int* __restrict__ bucketCount){
    __shared__ int cnt[256];
    cnt[threadIdx.x] = 0;
    __syncthreads();
    int base = blockIdx.x*CHUNK;
    int lim = min(base + CHUNK, E);
    for (int i = base + threadIdx.x; i < lim; i += 256)
        atomicAdd(&cnt[dst[i] >> BSHIFT], 1);
    __syncthreads();
    if (threadIdx.x < NB && cnt[threadIdx.x])
        atomicAdd(&bucketCount[threadIdx.x], cnt[threadIdx.x]);
}

__global__ __launch_bounds__(256) void k_bucket_scan(const int* __restrict__ bucketCount,
                                                     int NB, int E, int N,
                                                     int* __restrict__ bucketOff,
                                                     int* __restrict__ bucketCur,
                                                     int* __restrict__ rowptr){
    __shared__ int sums4[4];
    int v = (threadIdx.x < NB) ? bucketCount[threadIdx.x] : 0;
    int x = incl_scan256(v, sums4);
    if (threadIdx.x < NB){
        bucketOff[threadIdx.x] = x - v;
        bucketCur[threadIdx.x] = x - v;
    }
    if (threadIdx.x == NB-1) bucketOff[NB] = x;    // == E
    if (threadIdx.x == 0) rowptr[N] = E;
}

// bin (src,dst) pairs into buckets; LDS-staged so global writes are chunked/coalesced
__global__ __launch_bounds__(256) void k_bucket_place(const int* __restrict__ src,
                                                      const int* __restrict__ dst, int E, int NB,
                                                      int* __restrict__ bucketCur,
                                                      int2* __restrict__ pairs){
    __shared__ int cnt[256], binStart[256], binCur[256], chunkBase[256];
    __shared__ int sums4[4];
    __shared__ int2 lp[CHUNK];
    int tid = threadIdx.x;
    cnt[tid] = 0; binCur[tid] = 0;
    __syncthreads();
    int base = blockIdx.x*CHUNK;
    int s[16], d[16];
    #pragma unroll
    for (int k = 0; k < 16; ++k){
        int i = base + k*256 + tid;
        if (i < E){ s[k] = src[i]; d[k] = dst[i]; atomicAdd(&cnt[d[k] >> BSHIFT], 1); }
        else d[k] = -1;
    }
    __syncthreads();
    int v = cnt[tid];
    int x = incl_scan256(v, sums4);
    binStart[tid] = x - v;
    __syncthreads();
    #pragma unroll
    for (int k = 0; k < 16; ++k){
        if (d[k] >= 0){
            int b = d[k] >> BSHIFT;
            int p = binStart[b] + atomicAdd(&binCur[b], 1);
            lp[p] = make_int2(s[k], d[k]);
        }
    }
    if (tid < NB){
        int c = cnt[tid];
        chunkBase[tid] = c ? atomicAdd(&bucketCur[tid], c) : 0;
    }
    __syncthreads();
    int total = min(CHUNK, E - base);
    for (int i = tid; i < total; i += 256){
        int2 p = lp[i];
        int b = p.y >> BSHIFT;
        pairs[chunkBase[b] + (i - binStart[b])] = p;
    }
}

// one block per bucket: local deg/prefix -> rowptr segment + colarr (block-owned region)
__global__ __launch_bounds__(256) void k_bucket_csr(const int2* __restrict__ pairs,
                                                    const int* __restrict__ bucketOff, int N,
                                                    int* __restrict__ rowptr,
                                                    int* __restrict__ colarr){
    __shared__ int deg[512], cur[512];
    __shared__ int sums4[4];
    __shared__ int tAs;
    int b = blockIdx.x, tid = threadIdx.x;
    int d0 = b << BSHIFT;
    int e0 = bucketOff[b], e1 = bucketOff[b+1];
    deg[tid] = 0; deg[256+tid] = 0;
    __syncthreads();
    for (int i = e0 + tid; i < e1; i += 256)
        atomicAdd(&deg[pairs[i].y - d0], 1);
    __syncthreads();
    int vA = deg[tid], vB = deg[256+tid];
    int xA = incl_scan256(vA, sums4);
    if (tid == 255) tAs = xA;
    int xB = incl_scan256(vB, sums4) + tAs;
    int exclA = xA - vA, exclB = xB - vB;
    cur[tid] = exclA; cur[256+tid] = exclB;
    int dA = d0 + tid, dB = d0 + 256 + tid;
    if (dA < N) rowptr[dA] = e0 + exclA;
    if (dB < N) rowptr[dB] = e0 + exclB;
    __syncthreads();
    for (int i = e0 + tid; i < e1; i += 256){
        int2 p = pairs[i];
        int pos = e0 + atomicAdd(&cur[p.y - d0], 1);
        colarr[pos] = p.x;
    }
}

// ---------------- transforms ----------------
__global__ __launch_bounds__(256) void k_transform_in(const float* __restrict__ x,
                                                      const float* __restrict__ W,  // [3][64]
                                                      const float* __restrict__ a_src,
                                                      const float* __restrict__ a_dst,
                                                      unsigned short* __restrict__ hout,  // bf16
                                                      float* __restrict__ ssrc,
                                                      float* __restrict__ sdst, int N){
    int wv = blockIdx.x*4 + (threadIdx.x >> 6);
    int lane = threadIdx.x & 63;
    if (wv >= N) return;
    float acc = 0.f;
    #pragma unroll
    for (int k = 0; k < 3; ++k)
        acc += x[wv*3 + k] * W[k*64 + lane];
    hout[(size_t)wv*64 + lane] = f2bf(acc);
    float v1 = acc * a_src[lane];
    float v2 = acc * a_dst[lane];
    #pragma unroll
    for (int o = 32; o; o >>= 1){ v1 += __shfl_xor(v1, o, 64); v2 += __shfl_xor(v2, o, 64); }
    if (lane == 0){ ssrc[wv] = v1; sdst[wv] = v2; }
}

// MFMA transform: 64 rows/block; split-bf16 X@W ~= Xh@Wh + Xh@Wl + Xl@Wh.
// Scores computed from fp32 accumulators; h emitted as bf16 via LDS restage.
#define LDW 72
__global__ __launch_bounds__(256) void k_transform_h_mfma(const float* __restrict__ feat,
                                                          const float* __restrict__ vn,      // [256][64] or null
                                                          const float* __restrict__ vn_emb,  // used if vn null
                                                          const int* __restrict__ hb,
                                                          const float* __restrict__ W,       // [64][64]
                                                          const float* __restrict__ a_src,
                                                          const float* __restrict__ a_dst,
                                                          unsigned short* __restrict__ hout, // bf16
                                                          float* __restrict__ ssrc,
                                                          float* __restrict__ sdst, int N){
    __shared__ unsigned short WhT[64*LDW], WlT[64*LDW], Ah[64*LDW], Al[64*LDW];
    const int n0 = blockIdx.x * 64;

    for (int idx = threadIdx.x; idx < 4096; idx += 256){
        int n = idx >> 6, k = idx & 63;
        float w = W[k*64 + n];
        unsigned short hi = f2bf(w);
        WhT[n*LDW + k] = hi;
        WlT[n*LDW + k] = f2bf(w - bf2f(hi));
    }
    for (int t = threadIdx.x; t < 1024; t += 256){
        int row = t >> 4, c4 = t & 15;
        int node = n0 + row;
        float4 v = make_float4(0.f,0.f,0.f,0.f);
        if (node < N){
            v = ((const float4*)feat)[(size_t)node*16 + c4];
            float4 g = vn ? ((const float4*)vn)[(size_t)hb[node]*16 + c4]
                          : ((const float4*)vn_emb)[c4];
            v.x += g.x; v.y += g.y; v.z += g.z; v.w += g.w;
        }
        int base = row*LDW + c4*4;
        unsigned short h0 = f2bf(v.x), h1 = f2bf(v.y), h2 = f2bf(v.z), h3 = f2bf(v.w);
        Ah[base+0] = h0; Al[base+0] = f2bf(v.x - bf2f(h0));
        Ah[base+1] = h1; Al[base+1] = f2bf(v.y - bf2f(h1));
        Ah[base+2] = h2; Al[base+2] = f2bf(v.z - bf2f(h2));
        Ah[base+3] = h3; Al[base+3] = f2bf(v.w - bf2f(h3));
    }
    __syncthreads();

    int lane = threadIdx.x & 63;
    int wv   = threadIdx.x >> 6;
    int mrow = lane & 15, quad = lane >> 4;
    int m0 = wv * 16;

    f32x4 acc0 = {0,0,0,0}, acc1 = {0,0,0,0}, acc2 = {0,0,0,0}, acc3 = {0,0,0,0};
    #pragma unroll
    for (int k0 = 0; k0 < 64; k0 += 32){
        int kb = k0 + quad*8;
        short8 ah = *(const short8*)&Ah[(m0+mrow)*LDW + kb];
        short8 al = *(const short8*)&Al[(m0+mrow)*LDW + kb];
        short8 b0h = *(const short8*)&WhT[( 0+mrow)*LDW + kb];
        short8 b1h = *(const short8*)&WhT[(16+mrow)*LDW + kb];
        short8 b2h = *(const short8*)&WhT[(32+mrow)*LDW + kb];
        short8 b3h = *(const short8*)&WhT[(48+mrow)*LDW + kb];
        short8 b0l = *(const short8*)&WlT[( 0+mrow)*LDW + kb];
        short8 b1l = *(const short8*)&WlT[(16+mrow)*LDW + kb];
        short8 b2l = *(const short8*)&WlT[(32+mrow)*LDW + kb];
        short8 b3l = *(const short8*)&WlT[(48+mrow)*LDW + kb];
        acc0 = __builtin_amdgcn_mfma_f32_16x16x32_bf16(ah, b0h, acc0, 0, 0, 0);
        acc1 = __builtin_amdgcn_mfma_f32_16x16x32_bf16(ah, b1h, acc1, 0, 0, 0);
        acc2 = __builtin_amdgcn_mfma_f32_16x16x32_bf16(ah, b2h, acc2, 0, 0, 0);
        acc3 = __builtin_amdgcn_mfma_f32_16x16x32_bf16(ah, b3h, acc3, 0, 0, 0);
        acc0 = __builtin_amdgcn_mfma_f32_16x16x32_bf16(ah, b0l, acc0, 0, 0, 0);
        acc1 = __builtin_amdgcn_mfma_f32_16x16x32_bf16(ah, b1l, acc1, 0, 0, 0);
        acc2 = __builtin_amdgcn_mfma_f32_16x16x32_bf16(ah, b2l, acc2, 0, 0, 0);
        acc3 = __builtin_amdgcn_mfma_f32_16x16x32_bf16(ah, b3l, acc3, 0, 0, 0);
        acc0 = __builtin_amdgcn_mfma_f32_16x16x32_bf16(al, b0h, acc0, 0, 0, 0);
        acc1 = __builtin_amdgcn_mfma_f32_16x16x32_bf16(al, b1h, acc1, 0, 0, 0);
        acc2 = __builtin_amdgcn_mfma_f32_16x16x32_bf16(al, b2h, acc2, 0, 0, 0);
        acc3 = __builtin_amdgcn_mfma_f32_16x16x32_bf16(al, b3h, acc3, 0, 0, 0);
    }

    float as0 = a_src[mrow], as1 = a_src[16+mrow], as2 = a_src[32+mrow], as3 = a_src[48+mrow];
    float ad0 = a_dst[mrow], ad1 = a_dst[16+mrow], ad2 = a_dst[32+mrow], ad3 = a_dst[48+mrow];
    #pragma unroll
    for (int r = 0; r < 4; ++r){
        float p1 = acc0[r]*as0 + acc1[r]*as1 + acc2[r]*as2 + acc3[r]*as3;
        float p2 = acc0[r]*ad0 + acc1[r]*ad1 + acc2[r]*ad2 + acc3[r]*ad3;
        #pragma unroll
        for (int o = 8; o; o >>= 1){ p1 += __shfl_xor(p1, o, 64); p2 += __shfl_xor(p2, o, 64); }
        int node = n0 + m0 + quad*4 + r;
        if (mrow == 0 && node < N){ ssrc[node] = p1; sdst[node] = p2; }
    }
    // restage C as bf16 into this wave's own Ah rows (no cross-wave hazard),
    // then coalesced 16B row stores.
    #pragma unroll
    for (int r = 0; r < 4; ++r){
        int row = m0 + quad*4 + r;
        Ah[row*LDW + mrow     ] = f2bf(acc0[r]);
        Ah[row*LDW + mrow + 16] = f2bf(acc1[r]);
        Ah[row*LDW + mrow + 32] = f2bf(acc2[r]);
        Ah[row*LDW + mrow + 48] = f2bf(acc3[r]);
    }
    int r2 = lane >> 2, seg = lane & 3;
    int node = n0 + m0 + r2;
    if (node < N){
        short8 va = *(const short8*)&Ah[(m0+r2)*LDW + seg*16];
        short8 vb = *(const short8*)&Ah[(m0+r2)*LDW + seg*16 + 8];
        *(short8*)&hout[(size_t)node*64 + seg*16]     = va;
        *(short8*)&hout[(size_t)node*64 + seg*16 + 8] = vb;
    }
}

// ---------------- GAT aggregation ----------------
// One wave per dst. Phase A: 64 edge alphas in parallel + online-softmax merge.
// Phase B: quad-parallel bf16 row gathers (4 source rows per step, uint2/lane).
__global__ __launch_bounds__(256) void k_aggregate(const unsigned short* __restrict__ h,
                                                   const float* __restrict__ ssrc,
                                                   const float* __restrict__ sdst,
                                                   const int* __restrict__ rowptr,
                                                   const int* __restrict__ col,
                                                   const float* __restrict__ bias,
                                                   float* __restrict__ out, int N){
    __shared__ float2 swb[4][64];
    int wv = threadIdx.x >> 6;
    int d = blockIdx.x*4 + wv;
    int lane = threadIdx.x & 63;
    if (d >= N) return;
    int q = lane >> 4, c4 = lane & 15;
    float sd = sdst[d];
    float a0 = ssrc[d] + sd; a0 = (a0 < 0.f) ? 0.2f*a0 : a0;   // self loop seed
    float m = a0;
    float denom = 1.0f;
    float4 acc = make_float4(0.f,0.f,0.f,0.f);
    if (q == 0){
        uint2 u = *(const uint2*)&h[(size_t)d*64 + c4*4];
        acc.x = __uint_as_float(u.x << 16);
        acc.y = __uint_as_float(u.x & 0xffff0000u);
        acc.z = __uint_as_float(u.y << 16);
        acc.w = __uint_as_float(u.y & 0xffff0000u);
    }
    int e0 = rowptr[d], e1 = rowptr[d+1];
    for (int base = e0; base < e1; base += 64){
        int ne = min(64, e1 - base);
        int s = 0; float a = -1e30f;
        if (lane < ne){
            s = col[base + lane];
            a = ssrc[s] + sd; a = (a < 0.f) ? 0.2f*a : a;
        }
        float cm = a;
        #pragma unroll
        for (int o = 32; o; o >>= 1) cm = fmaxf(cm, __shfl_xor(cm, o, 64));
        float nm = fmaxf(m, cm);
        float w = (lane < ne) ? __expf(a - nm) : 0.f;
        float csum = w;
        #pragma unroll
        for (int o = 32; o; o >>= 1) csum += __shfl_xor(csum, o, 64);
        float sc = __expf(m - nm);
        denom = denom*sc + csum;
        acc.x *= sc; acc.y *= sc; acc.z *= sc; acc.w *= sc;
        m = nm;
        swb[wv][lane] = make_float2(w, __int_as_float(s));
        for (int j = 0; j < ne; j += 4){
            float2 p = swb[wv][j + q];
            int sj = __float_as_int(p.y);
            uint2 u = *(const uint2*)&h[(size_t)sj*64 + c4*4];
            acc.x += p.x * __uint_as_float(u.x << 16);
            acc.y += p.x * __uint_as_float(u.x & 0xffff0000u);
            acc.z += p.x * __uint_as_float(u.y << 16);
            acc.w += p.x * __uint_as_float(u.y & 0xffff0000u);
        }
    }
    #pragma unroll
    for (int o = 16; o <= 32; o <<= 1){
        acc.x += __shfl_xor(acc.x, o, 64);
        acc.y += __shfl_xor(acc.y, o, 64);
        acc.z += __shfl_xor(acc.z, o, 64);
        acc.w += __shfl_xor(acc.w, o, 64);
    }
    if (q == 0){
        float4 b4 = ((const float4*)bias)[c4];
        float inv = 1.0f/denom;
        ((float4*)out)[(size_t)d*16 + c4] =
            make_float4(acc.x*inv + b4.x, acc.y*inv + b4.y,
                        acc.z*inv + b4.z, acc.w*inv + b4.w);
    }
}

// ---------------- virtual-node stage ----------------
__global__ __launch_bounds__(256) void k_vn_segsum(const float* __restrict__ outA,
                                                   const int* __restrict__ hb, int N,
                                                   const float* __restrict__ vd_old,
                                                   const float* __restrict__ root_old,
                                                   const float* __restrict__ vn_emb,
                                                   float* __restrict__ vw,             // [257][64]
                                                   float* __restrict__ colsum){        // zeroed
    __shared__ float part[4][64];
    int b = blockIdx.x;
    int wv = threadIdx.x >> 6, lane = threadIdx.x & 63;
    int nq = N >> 2;
    int nqp = (nq + 255) & ~255;
    float acc = 0.f;
    for (int q0 = 0; q0 < nqp; q0 += 256){
        int q = q0 + threadIdx.x;
        int4 v = make_int4(-1,-1,-1,-1);
        if (q < nq) v = ((const int4*)hb)[q];
        unsigned long long m0 = __ballot(v.x == b);
        unsigned long long m1 = __ballot(v.y == b);
        unsigned long long m2 = __ballot(v.z == b);
        unsigned long long m3 = __ballot(v.w == b);
        int qbase = q - lane;
        while (m0){ int l = __ffsll(m0)-1; m0 &= m0-1; acc += outA[(size_t)((qbase+l)*4+0)*64 + lane]; }
        while (m1){ int l = __ffsll(m1)-1; m1 &= m1-1; acc += outA[(size_t)((qbase+l)*4+1)*64 + lane]; }
        while (m2){ int l = __ffsll(m2)-1; m2 &= m2-1; acc += outA[(size_t)((qbase+l)*4+2)*64 + lane]; }
        while (m3){ int l = __ffsll(m3)-1; m3 &= m3-1; acc += outA[(size_t)((qbase+l)*4+3)*64 + lane]; }
    }
    if (wv == 0)
        for (int t = nq*4; t < N; ++t)
            if (hb[t] == b) acc += outA[(size_t)t*64 + lane];
    part[wv][lane] = acc;
    __syncthreads();
    if (wv == 0){
        float v = part[0][lane] + part[1][lane] + part[2][lane] + part[3][lane];
        float old  = vd_old   ? vd_old[b*64 + lane] : vn_emb[lane];
        float rold = root_old ? root_old[lane]      : vn_emb[lane];
        v += old + rold;
        vw[b*64 + lane] = v;
        atomicAdd(&colsum[lane], v);
    }
}

// fused: root assembly + L x (Linear-ReLU-Linear-ReLU) over 257 independent rows
__global__ __launch_bounds__(256) void k_vn_mlp(const float* __restrict__ colsum,
                                                const float* __restrict__ root_old,
                                                const float* __restrict__ vn_emb,
                                                const float* __restrict__ mlp_w1,
                                                const float* __restrict__ mlp_b1,
                                                const float* __restrict__ mlp_w2,
                                                const float* __restrict__ mlp_b2,
                                                int L, float* __restrict__ vw){
    __shared__ float Wl[64*64];
    int wv = blockIdx.x*4 + (threadIdx.x >> 6);
    int lane = threadIdx.x & 63;
    bool valid = (wv < 257);
    float iv = 0.f;
    if (valid){
        if (wv == 256){
            float rold = root_old ? root_old[lane] : vn_emb[lane];
            iv = colsum[lane] + rold;            // vn_root = colsum + vn_root_old
        } else {
            iv = vw[wv*64 + lane];
        }
    }
    for (int m = 0; m < L; ++m){
        #pragma unroll
        for (int half = 0; half < 2; ++half){
            const float* W    = (half ? mlp_w2 : mlp_w1) + (size_t)m*4096;
            const float* bias = (half ? mlp_b2 : mlp_b1) + (size_t)m*64;
            __syncthreads();
            for (int i = threadIdx.x; i < 4096; i += 256) Wl[i] = W[i];
            __syncthreads();
            float acc = bias[lane];
            #pragma unroll
            for (int k = 0; k < 64; ++k)
                acc += __shfl(iv, k, 64) * Wl[k*64 + lane];
            iv = fmaxf(acc, 0.f);
        }
    }
    if (valid) vw[wv*64 + lane] = iv;
}

extern "C" void kernel_launch(void* const* d_in, const int* in_sizes, int n_in,
                              void* d_out, int out_size, void* d_ws, size_t ws_size,
                              hipStream_t stream) {
    const int N = in_sizes[0] / 3;
    const int E = in_sizes[1] / 2;
    const int L = in_sizes[9] / (64*64);
    const int NB = (N + (1<<BSHIFT) - 1) >> BSHIFT;   // buckets (<=256 for N<=131072)

    const float* x        = (const float*)d_in[0];
    const int*   edge     = (const int*)d_in[1];
    const int*   srcp     = edge;
    const int*   dstp     = edge + E;
    const int*   hb       = (const int*)d_in[2];
    const float* w_in     = (const float*)d_in[5];
    const float* a_src_in = (const float*)d_in[6];
    const float* a_dst_in = (const float*)d_in[7];
    const float* b_in     = (const float*)d_in[8];
    const float* w_l      = (const float*)d_in[9];
    const float* a_src_l  = (const float*)d_in[10];
    const float* a_dst_l  = (const float*)d_in[11];
    const float* b_l      = (const float*)d_in[12];
    const float* mlp_w1   = (const float*)d_in[13];
    const float* mlp_b1   = (const float*)d_in[14];
    const float* mlp_w2   = (const float*)d_in[15];
    const float* mlp_b2   = (const float*)d_in[16];
    const float* vn_emb   = (const float*)d_in[17];
    float*       out      = (float*)d_out;

    // ---- workspace carve (256B-aligned) ----
    char* ws = (char*)d_ws;
    size_t off = 0;
    auto carve = [&](size_t bytes) -> char* {
        char* p = ws + off;
        off = (off + bytes + 255) & ~(size_t)255;
        return p;
    };
    unsigned short* h = (unsigned short*)carve((size_t)N*64*2);  // bf16; aliased as pairs in CSR build
    float* outA   = (float*)carve((size_t)N*64*4);
    float* ssrc   = (float*)carve((size_t)N*4);
    float* sdst   = (float*)carve((size_t)N*4);
    int*   rowptr = (int*)carve((size_t)(N+1)*4);
    char*  zstart = ws + off;
    int*   bucketCount = (int*)carve(256*4);
    float* colsum = (float*)carve(64*4);
    size_t zbytes = (size_t)((ws + off) - zstart);
    int*   bucketOff = (int*)carve(257*4);
    int*   bucketCur = (int*)carve(256*4);
    int*   colarr = (int*)carve((size_t)E*4);
    float* vw     = (float*)carve((size_t)257*64*4);
    if (off > ws_size) return;
    int2* pairs = (int2*)h;   // E*8 bytes <= N*128 bytes; pairs dead before h's first write

    // ---- CSR build (bucketed) ----
    hipMemsetAsync(zstart, 0, zbytes, stream);
    const int nchunk = (E + CHUNK - 1) / CHUNK;
    k_bucket_count<<<nchunk, 256, 0, stream>>>(dstp, E, NB, bucketCount);
    k_bucket_scan <<<1, 256, 0, stream>>>(bucketCount, NB, E, N, bucketOff, bucketCur, rowptr);
    k_bucket_place<<<nchunk, 256, 0, stream>>>(srcp, dstp, E, NB, bucketCur, pairs);
    k_bucket_csr  <<<NB, 256, 0, stream>>>(pairs, bucketOff, N, rowptr, colarr);

    const int nwb = (N + 3) / 4;     // wave-per-node kernels
    const int nmb = (N + 63) / 64;   // mfma transform blocks

    // ---- GAT layer 0 (IN -> H) ----
    k_transform_in<<<nwb, 256, 0, stream>>>(x, w_in, a_src_in, a_dst_in, h, ssrc, sdst, N);
    k_aggregate<<<nwb, 256, 0, stream>>>(h, ssrc, sdst, rowptr, colarr, b_in, outA, N);

    // ---- hidden layers ----
    for (int l = 0; l < L; ++l){
        const float* vnp = (l == 0) ? nullptr : vw;
        k_transform_h_mfma<<<nmb, 256, 0, stream>>>(outA, vnp, vn_emb, hb,
                                                    w_l + (size_t)l*4096,
                                                    a_src_l + (size_t)l*64,
                                                    a_dst_l + (size_t)l*64,
                                                    h, ssrc, sdst, N);
        const bool last = (l == L-1);
        float* dst_buf = last ? out : outA;
        k_aggregate<<<nwb, 256, 0, stream>>>(h, ssrc, sdst, rowptr, colarr,
                                             b_l + (size_t)l*64, dst_buf, N);
        if (!last){
            const float* vdo = (l == 0) ? nullptr : vw;
            const float* ro  = (l == 0) ? nullptr : (vw + 256*64);
            k_vn_segsum<<<256, 256, 0, stream>>>(outA, hb, N, vdo, ro, vn_emb, vw, colsum);
            k_vn_mlp<<<(257+3)/4, 256, 0, stream>>>(colsum, ro, vn_emb,
                                                    mlp_w1, mlp_b1, mlp_w2, mlp_b2, L, vw);
        }
    }
}

// Round 7
// 420.065 us; speedup vs baseline: 2.6964x; 1.0498x over previous
//
#include <hip/hip_runtime.h>

// GNN with hierarchical virtual nodes. FP32 in/out, int32 indices.
//
//  CSR build: bucketed (dst>>9) two-level sort -> per-bucket-owned colarr
//  regions (kills the 64B-line write amplification of random scatter).
//  Node list grouped by hb (counting sort) for the VN segment-sum.
//  h stored BF16 (halves random-gather traffic); scores fp32.
//  Aggregate softmax uses the self-loop alpha as fixed reference (no online
//  max): softmax is shift-invariant, exp args bounded ~1e2 << fp32 range.
//  (VN update after the last layer never reaches the output -> skipped)

typedef __attribute__((ext_vector_type(8))) short short8;
typedef __attribute__((ext_vector_type(4))) float f32x4;

__device__ __forceinline__ unsigned short f2bf(float x){      // RNE float->bf16
    unsigned u = __float_as_uint(x);
    unsigned r = (u + 0x7fffu + ((u >> 16) & 1u)) >> 16;
    return (unsigned short)r;
}
__device__ __forceinline__ float bf2f(unsigned short b){
    return __uint_as_float(((unsigned)b) << 16);
}

#define BSHIFT 9
#define CHUNK 4096
#define NSLICE 8

// inclusive scan of v across the 256 threads of the block (4 waves)
__device__ __forceinline__ int incl_scan256(int v, int* sums4){
    int lane = threadIdx.x & 63, w = threadIdx.x >> 6;
    int x = v;
    #pragma unroll
    for (int o = 1; o < 64; o <<= 1){ int t = __shfl_up(x, o, 64); if (lane >= o) x += t; }
    __syncthreads();                 // protect sums4 reuse across calls
    if (lane == 63) sums4[w] = x;
    __syncthreads();
    for (int j = 0; j < w; ++j) x += sums4[j];
    return x;
}

// ---------------- bucketed CSR build ----------------
__global__ __launch_bounds__(256) void k_bucket_count(const int* __restrict__ dst, int E, int NB,
                                                      int* __restrict__ bucketCount){
    __shared__ int cnt[256];
    cnt[threadIdx.x] = 0;
    __syncthreads();
    int base = blockIdx.x*CHUNK;
    int lim = min(base + CHUNK, E);
    for (int i = base + threadIdx.x; i < lim; i += 256)
        atomicAdd(&cnt[dst[i] >> BSHIFT], 1);
    __syncthreads();
    if (threadIdx.x < NB && cnt[threadIdx.x])
        atomicAdd(&bucketCount[threadIdx.x], cnt[threadIdx.x]);
}

__global__ __launch_bounds__(256) void k_hb_count(const int* __restrict__ hb, int N,
                                                  int* __restrict__ hbBins){
    __shared__ int cnt[256];
    cnt[threadIdx.x] = 0;
    __syncthreads();
    int base = blockIdx.x*CHUNK;
    int lim = min(base + CHUNK, N);
    for (int i = base + threadIdx.x; i < lim; i += 256)
        atomicAdd(&cnt[hb[i]], 1);
    __syncthreads();
    if (cnt[threadIdx.x])
        atomicAdd(&hbBins[threadIdx.x], cnt[threadIdx.x]);
}

// one block: scans graph buckets AND hb bins
__global__ __launch_bounds__(256) void k_scan_all(const int* __restrict__ bucketCount,
                                                  int NB, int E, int N,
                                                  int* __restrict__ bucketOff,
                                                  int* __restrict__ bucketCur,
                                                  int* __restrict__ rowptr,
                                                  const int* __restrict__ hbBins,
                                                  int* __restrict__ binptr,
                                                  int* __restrict__ bincur){
    __shared__ int sums4[4];
    int tid = threadIdx.x;
    int v = (tid < NB) ? bucketCount[tid] : 0;
    int x = incl_scan256(v, sums4);
    if (tid < NB){ bucketOff[tid] = x - v; bucketCur[tid] = x - v; }
    if (tid == NB-1) bucketOff[NB] = x;    // == E
    if (tid == 0) rowptr[N] = E;
    int v2 = hbBins[tid];
    int x2 = incl_scan256(v2, sums4);
    binptr[tid] = x2 - v2;
    bincur[tid] = x2 - v2;
    if (tid == 255) binptr[256] = x2;      // == N
}

// bin (src,dst) pairs into buckets; LDS-staged so global writes are chunked/coalesced
__global__ __launch_bounds__(256) void k_bucket_place(const int* __restrict__ src,
                                                      const int* __restrict__ dst, int E, int NB,
                                                      int* __restrict__ bucketCur,
                                                      int2* __restrict__ pairs){
    __shared__ int cnt[256], binStart[256], binCur[256], chunkBase[256];
    __shared__ int sums4[4];
    __shared__ int2 lp[CHUNK];
    int tid = threadIdx.x;
    cnt[tid] = 0; binCur[tid] = 0;
    __syncthreads();
    int base = blockIdx.x*CHUNK;
    int s[16], d[16];
    #pragma unroll
    for (int k = 0; k < 16; ++k){
        int i = base + k*256 + tid;
        if (i < E){ s[k] = src[i]; d[k] = dst[i]; atomicAdd(&cnt[d[k] >> BSHIFT], 1); }
        else d[k] = -1;
    }
    __syncthreads();
    int v = cnt[tid];
    int x = incl_scan256(v, sums4);
    binStart[tid] = x - v;
    __syncthreads();
    #pragma unroll
    for (int k = 0; k < 16; ++k){
        if (d[k] >= 0){
            int b = d[k] >> BSHIFT;
            int p = binStart[b] + atomicAdd(&binCur[b], 1);
            lp[p] = make_int2(s[k], d[k]);
        }
    }
    if (tid < NB){
        int c = cnt[tid];
        chunkBase[tid] = c ? atomicAdd(&bucketCur[tid], c) : 0;
    }
    __syncthreads();
    int total = min(CHUNK, E - base);
    for (int i = tid; i < total; i += 256){
        int2 p = lp[i];
        int b = p.y >> BSHIFT;
        pairs[chunkBase[b] + (i - binStart[b])] = p;
    }
}

// nodes grouped by hb bin (counting sort, LDS-staged writes)
__global__ __launch_bounds__(256) void k_hb_place(const int* __restrict__ hb, int N,
                                                  int* __restrict__ bincur,
                                                  int* __restrict__ nodes){
    __shared__ int cnt[256], binStart[256], binCur[256], chunkBase[256];
    __shared__ int sums4[4];
    __shared__ int lp[CHUNK];
    __shared__ unsigned char lb[CHUNK];
    int tid = threadIdx.x;
    cnt[tid] = 0; binCur[tid] = 0;
    __syncthreads();
    int base = blockIdx.x*CHUNK;
    int key[16];
    #pragma unroll
    for (int k = 0; k < 16; ++k){
        int i = base + k*256 + tid;
        key[k] = (i < N) ? hb[i] : -1;
        if (key[k] >= 0) atomicAdd(&cnt[key[k]], 1);
    }
    __syncthreads();
    int v = cnt[tid];
    int x = incl_scan256(v, sums4);
    binStart[tid] = x - v;
    __syncthreads();
    #pragma unroll
    for (int k = 0; k < 16; ++k){
        if (key[k] >= 0){
            int p = binStart[key[k]] + atomicAdd(&binCur[key[k]], 1);
            lp[p] = base + k*256 + tid;
            lb[p] = (unsigned char)key[k];
        }
    }
    if (cnt[tid]) chunkBase[tid] = atomicAdd(&bincur[tid], cnt[tid]);
    __syncthreads();
    int total = min(CHUNK, N - base);
    for (int i = tid; i < total; i += 256){
        int b = lb[i];
        nodes[chunkBase[b] + (i - binStart[b])] = lp[i];
    }
}

// one block per bucket: local deg/prefix -> rowptr segment + colarr (block-owned region)
__global__ __launch_bounds__(256) void k_bucket_csr(const int2* __restrict__ pairs,
                                                    const int* __restrict__ bucketOff, int N,
                                                    int* __restrict__ rowptr,
                                                    int* __restrict__ colarr){
    __shared__ int deg[512], cur[512];
    __shared__ int sums4[4];
    __shared__ int tAs;
    int b = blockIdx.x, tid = threadIdx.x;
    int d0 = b << BSHIFT;
    int e0 = bucketOff[b], e1 = bucketOff[b+1];
    deg[tid] = 0; deg[256+tid] = 0;
    __syncthreads();
    for (int i = e0 + tid; i < e1; i += 256)
        atomicAdd(&deg[pairs[i].y - d0], 1);
    __syncthreads();
    int vA = deg[tid], vB = deg[256+tid];
    int xA = incl_scan256(vA, sums4);
    if (tid == 255) tAs = xA;
    int xB = incl_scan256(vB, sums4) + tAs;
    int exclA = xA - vA, exclB = xB - vB;
    cur[tid] = exclA; cur[256+tid] = exclB;
    int dA = d0 + tid, dB = d0 + 256 + tid;
    if (dA < N) rowptr[dA] = e0 + exclA;
    if (dB < N) rowptr[dB] = e0 + exclB;
    __syncthreads();
    for (int i = e0 + tid; i < e1; i += 256){
        int2 p = pairs[i];
        int pos = e0 + atomicAdd(&cur[p.y - d0], 1);
        colarr[pos] = p.x;
    }
}

// ---------------- transforms ----------------
__global__ __launch_bounds__(256) void k_transform_in(const float* __restrict__ x,
                                                      const float* __restrict__ W,  // [3][64]
                                                      const float* __restrict__ a_src,
                                                      const float* __restrict__ a_dst,
                                                      unsigned short* __restrict__ hout,  // bf16
                                                      float* __restrict__ ssrc,
                                                      float* __restrict__ sdst, int N){
    int wv = blockIdx.x*4 + (threadIdx.x >> 6);
    int lane = threadIdx.x & 63;
    if (wv >= N) return;
    float acc = 0.f;
    #pragma unroll
    for (int k = 0; k < 3; ++k)
        acc += x[wv*3 + k] * W[k*64 + lane];
    hout[(size_t)wv*64 + lane] = f2bf(acc);
    float v1 = acc * a_src[lane];
    float v2 = acc * a_dst[lane];
    #pragma unroll
    for (int o = 32; o; o >>= 1){ v1 += __shfl_xor(v1, o, 64); v2 += __shfl_xor(v2, o, 64); }
    if (lane == 0){ ssrc[wv] = v1; sdst[wv] = v2; }
}

// MFMA transform: 64 rows/block; split-bf16 X@W ~= Xh@Wh + Xh@Wl + Xl@Wh.
// Scores computed from fp32 accumulators; h emitted as bf16 via LDS restage.
#define LDW 72
__global__ __launch_bounds__(256) void k_transform_h_mfma(const float* __restrict__ feat,
                                                          const float* __restrict__ vn,      // [256][64] or null
                                                          const float* __restrict__ vn_emb,  // used if vn null
                                                          const int* __restrict__ hb,
                                                          const float* __restrict__ W,       // [64][64]
                                                          const float* __restrict__ a_src,
                                                          const float* __restrict__ a_dst,
                                                          unsigned short* __restrict__ hout, // bf16
                                                          float* __restrict__ ssrc,
                                                          float* __restrict__ sdst, int N){
    __shared__ unsigned short WhT[64*LDW], WlT[64*LDW], Ah[64*LDW], Al[64*LDW];
    const int n0 = blockIdx.x * 64;

    for (int idx = threadIdx.x; idx < 4096; idx += 256){
        int n = idx >> 6, k = idx & 63;
        float w = W[k*64 + n];
        unsigned short hi = f2bf(w);
        WhT[n*LDW + k] = hi;
        WlT[n*LDW + k] = f2bf(w - bf2f(hi));
    }
    for (int t = threadIdx.x; t < 1024; t += 256){
        int row = t >> 4, c4 = t & 15;
        int node = n0 + row;
        float4 v = make_float4(0.f,0.f,0.f,0.f);
        if (node < N){
            v = ((const float4*)feat)[(size_t)node*16 + c4];
            float4 g = vn ? ((const float4*)vn)[(size_t)hb[node]*16 + c4]
                          : ((const float4*)vn_emb)[c4];
            v.x += g.x; v.y += g.y; v.z += g.z; v.w += g.w;
        }
        int base = row*LDW + c4*4;
        unsigned short h0 = f2bf(v.x), h1 = f2bf(v.y), h2 = f2bf(v.z), h3 = f2bf(v.w);
        Ah[base+0] = h0; Al[base+0] = f2bf(v.x - bf2f(h0));
        Ah[base+1] = h1; Al[base+1] = f2bf(v.y - bf2f(h1));
        Ah[base+2] = h2; Al[base+2] = f2bf(v.z - bf2f(h2));
        Ah[base+3] = h3; Al[base+3] = f2bf(v.w - bf2f(h3));
    }
    __syncthreads();

    int lane = threadIdx.x & 63;
    int wv   = threadIdx.x >> 6;
    int mrow = lane & 15, quad = lane >> 4;
    int m0 = wv * 16;

    f32x4 acc0 = {0,0,0,0}, acc1 = {0,0,0,0}, acc2 = {0,0,0,0}, acc3 = {0,0,0,0};
    #pragma unroll
    for (int k0 = 0; k0 < 64; k0 += 32){
        int kb = k0 + quad*8;
        short8 ah = *(const short8*)&Ah[(m0+mrow)*LDW + kb];
        short8 al = *(const short8*)&Al[(m0+mrow)*LDW + kb];
        short8 b0h = *(const short8*)&WhT[( 0+mrow)*LDW + kb];
        short8 b1h = *(const short8*)&WhT[(16+mrow)*LDW + kb];
        short8 b2h = *(const short8*)&WhT[(32+mrow)*LDW + kb];
        short8 b3h = *(const short8*)&WhT[(48+mrow)*LDW + kb];
        short8 b0l = *(const short8*)&WlT[( 0+mrow)*LDW + kb];
        short8 b1l = *(const short8*)&WlT[(16+mrow)*LDW + kb];
        short8 b2l = *(const short8*)&WlT[(32+mrow)*LDW + kb];
        short8 b3l = *(const short8*)&WlT[(48+mrow)*LDW + kb];
        acc0 = __builtin_amdgcn_mfma_f32_16x16x32_bf16(ah, b0h, acc0, 0, 0, 0);
        acc1 = __builtin_amdgcn_mfma_f32_16x16x32_bf16(ah, b1h, acc1, 0, 0, 0);
        acc2 = __builtin_amdgcn_mfma_f32_16x16x32_bf16(ah, b2h, acc2, 0, 0, 0);
        acc3 = __builtin_amdgcn_mfma_f32_16x16x32_bf16(ah, b3h, acc3, 0, 0, 0);
        acc0 = __builtin_amdgcn_mfma_f32_16x16x32_bf16(ah, b0l, acc0, 0, 0, 0);
        acc1 = __builtin_amdgcn_mfma_f32_16x16x32_bf16(ah, b1l, acc1, 0, 0, 0);
        acc2 = __builtin_amdgcn_mfma_f32_16x16x32_bf16(ah, b2l, acc2, 0, 0, 0);
        acc3 = __builtin_amdgcn_mfma_f32_16x16x32_bf16(ah, b3l, acc3, 0, 0, 0);
        acc0 = __builtin_amdgcn_mfma_f32_16x16x32_bf16(al, b0h, acc0, 0, 0, 0);
        acc1 = __builtin_amdgcn_mfma_f32_16x16x32_bf16(al, b1h, acc1, 0, 0, 0);
        acc2 = __builtin_amdgcn_mfma_f32_16x16x32_bf16(al, b2h, acc2, 0, 0, 0);
        acc3 = __builtin_amdgcn_mfma_f32_16x16x32_bf16(al, b3h, acc3, 0, 0, 0);
    }

    float as0 = a_src[mrow], as1 = a_src[16+mrow], as2 = a_src[32+mrow], as3 = a_src[48+mrow];
    float ad0 = a_dst[mrow], ad1 = a_dst[16+mrow], ad2 = a_dst[32+mrow], ad3 = a_dst[48+mrow];
    #pragma unroll
    for (int r = 0; r < 4; ++r){
        float p1 = acc0[r]*as0 + acc1[r]*as1 + acc2[r]*as2 + acc3[r]*as3;
        float p2 = acc0[r]*ad0 + acc1[r]*ad1 + acc2[r]*ad2 + acc3[r]*ad3;
        #pragma unroll
        for (int o = 8; o; o >>= 1){ p1 += __shfl_xor(p1, o, 64); p2 += __shfl_xor(p2, o, 64); }
        int node = n0 + m0 + quad*4 + r;
        if (mrow == 0 && node < N){ ssrc[node] = p1; sdst[node] = p2; }
    }
    // restage C as bf16 into this wave's own Ah rows, then coalesced row stores
    #pragma unroll
    for (int r = 0; r < 4; ++r){
        int row = m0 + quad*4 + r;
        Ah[row*LDW + mrow     ] = f2bf(acc0[r]);
        Ah[row*LDW + mrow + 16] = f2bf(acc1[r]);
        Ah[row*LDW + mrow + 32] = f2bf(acc2[r]);
        Ah[row*LDW + mrow + 48] = f2bf(acc3[r]);
    }
    int r2 = lane >> 2, seg = lane & 3;
    int node = n0 + m0 + r2;
    if (node < N){
        short8 va = *(const short8*)&Ah[(m0+r2)*LDW + seg*16];
        short8 vb = *(const short8*)&Ah[(m0+r2)*LDW + seg*16 + 8];
        *(short8*)&hout[(size_t)node*64 + seg*16]     = va;
        *(short8*)&hout[(size_t)node*64 + seg*16 + 8] = vb;
    }
}

// ---------------- GAT aggregation ----------------
// One wave per dst. Softmax referenced to self-loop alpha (shift-invariant,
// no online max). Phase B: quad-parallel bf16 row gathers.
__global__ __launch_bounds__(256) void k_aggregate(const unsigned short* __restrict__ h,
                                                   const float* __restrict__ ssrc,
                                                   const float* __restrict__ sdst,
                                                   const int* __restrict__ rowptr,
                                                   const int* __restrict__ col,
                                                   const float* __restrict__ bias,
                                                   float* __restrict__ out, int N){
    __shared__ float2 swb[4][64];
    int wv = threadIdx.x >> 6;
    int d = blockIdx.x*4 + wv;
    int lane = threadIdx.x & 63;
    if (d >= N) return;
    int q = lane >> 4, c4 = lane & 15;
    float sd = sdst[d];
    float a0 = ssrc[d] + sd; a0 = (a0 < 0.f) ? 0.2f*a0 : a0;   // self loop reference
    float dlocal = 0.f;
    float4 acc = make_float4(0.f,0.f,0.f,0.f);
    if (q == 0){                                               // self loop, weight 1
        uint2 u = *(const uint2*)&h[(size_t)d*64 + c4*4];
        acc.x = __uint_as_float(u.x << 16);
        acc.y = __uint_as_float(u.x & 0xffff0000u);
        acc.z = __uint_as_float(u.y << 16);
        acc.w = __uint_as_float(u.y & 0xffff0000u);
    }
    int e0 = rowptr[d], e1 = rowptr[d+1];
    for (int base = e0; base < e1; base += 64){
        int ne = min(64, e1 - base);
        float w = 0.f; int s = 0;
        if (lane < ne){
            s = col[base + lane];
            float a = ssrc[s] + sd; a = (a < 0.f) ? 0.2f*a : a;
            w = __expf(a - a0);
        }
        dlocal += w;
        swb[wv][lane] = make_float2(w, __int_as_float(s));
        for (int j = 0; j < ne; j += 4){
            float2 p = swb[wv][j + q];
            int sj = __float_as_int(p.y);
            uint2 u = *(const uint2*)&h[(size_t)sj*64 + c4*4];
            acc.x += p.x * __uint_as_float(u.x << 16);
            acc.y += p.x * __uint_as_float(u.x & 0xffff0000u);
            acc.z += p.x * __uint_as_float(u.y << 16);
            acc.w += p.x * __uint_as_float(u.y & 0xffff0000u);
        }
    }
    #pragma unroll
    for (int o = 32; o; o >>= 1) dlocal += __shfl_xor(dlocal, o, 64);
    float denom = 1.0f + dlocal;
    #pragma unroll
    for (int o = 16; o <= 32; o <<= 1){
        acc.x += __shfl_xor(acc.x, o, 64);
        acc.y += __shfl_xor(acc.y, o, 64);
        acc.z += __shfl_xor(acc.z, o, 64);
        acc.w += __shfl_xor(acc.w, o, 64);
    }
    if (q == 0){
        float4 b4 = ((const float4*)bias)[c4];
        float inv = 1.0f/denom;
        ((float4*)out)[(size_t)d*16 + c4] =
            make_float4(acc.x*inv + b4.x, acc.y*inv + b4.y,
                        acc.z*inv + b4.z, acc.w*inv + b4.w);
    }
}

// ---------------- virtual-node stage ----------------
// grid = 256 bins x NSLICE slices; each block sums its slice's rows, writes partial
__global__ __launch_bounds__(256) void k_vn_segsum2(const float* __restrict__ outA,
                                                    const int* __restrict__ nodes,
                                                    const int* __restrict__ binptr,
                                                    float* __restrict__ vseg){   // [256*NSLICE][64]
    __shared__ float part[4][64];
    int b = blockIdx.x >> 3, s = blockIdx.x & (NSLICE-1);
    int wv = threadIdx.x >> 6, lane = threadIdx.x & 63;
    int i0 = binptr[b], i1 = binptr[b+1];
    int len = i1 - i0;
    int lo = i0 + (len*s)/NSLICE;
    int hi = i0 + (len*(s+1))/NSLICE;
    float acc = 0.f;
    for (int i = lo + wv; i < hi; i += 4){
        int n = nodes[i];
        acc += outA[(size_t)n*64 + lane];
    }
    part[wv][lane] = acc;
    __syncthreads();
    if (threadIdx.x < 64)
        vseg[(size_t)blockIdx.x*64 + lane] =
            part[0][lane] + part[1][lane] + part[2][lane] + part[3][lane];
}

// one block: vn_direct = segsum + old + root_old; root = colsum + root_old
__global__ __launch_bounds__(256) void k_vn_combine(const float* __restrict__ vseg,
                                                    const float* __restrict__ vd_old,
                                                    const float* __restrict__ root_old,
                                                    const float* __restrict__ vn_emb,
                                                    float* __restrict__ vw){   // [257][64]
    __shared__ float part[4][64];
    int wv = threadIdx.x >> 6, lane = threadIdx.x & 63;
    float rold = root_old ? root_old[lane] : vn_emb[lane];
    float emb  = vn_emb[lane];
    float csum = 0.f;
    for (int b = wv*64; b < wv*64 + 64; ++b){
        float v = 0.f;
        #pragma unroll
        for (int s = 0; s < NSLICE; ++s)
            v += vseg[(size_t)(b*NSLICE + s)*64 + lane];
        v += (vd_old ? vd_old[b*64 + lane] : emb) + rold;
        vw[b*64 + lane] = v;
        csum += v;
    }
    part[wv][lane] = csum;
    __syncthreads();
    if (threadIdx.x < 64)
        vw[256*64 + lane] = part[0][lane] + part[1][lane] + part[2][lane] + part[3][lane] + rold;
}

// fused: L x (Linear-ReLU-Linear-ReLU) over 257 independent rows (in place)
__global__ __launch_bounds__(256) void k_vn_mlp(const float* __restrict__ mlp_w1,
                                                const float* __restrict__ mlp_b1,
                                                const float* __restrict__ mlp_w2,
                                                const float* __restrict__ mlp_b2,
                                                int L, float* __restrict__ vw){
    __shared__ float Wl[64*64];
    int wv = blockIdx.x*4 + (threadIdx.x >> 6);
    int lane = threadIdx.x & 63;
    bool valid = (wv < 257);
    float iv = valid ? vw[wv*64 + lane] : 0.f;
    for (int m = 0; m < L; ++m){
        #pragma unroll
        for (int half = 0; half < 2; ++half){
            const float* W    = (half ? mlp_w2 : mlp_w1) + (size_t)m*4096;
            const float* bias = (half ? mlp_b2 : mlp_b1) + (size_t)m*64;
            __syncthreads();
            for (int i = threadIdx.x; i < 4096; i += 256) Wl[i] = W[i];
            __syncthreads();
            float acc = bias[lane];
            #pragma unroll
            for (int k = 0; k < 64; ++k)
                acc += __shfl(iv, k, 64) * Wl[k*64 + lane];
            iv = fmaxf(acc, 0.f);
        }
    }
    if (valid) vw[wv*64 + lane] = iv;
}

extern "C" void kernel_launch(void* const* d_in, const int* in_sizes, int n_in,
                              void* d_out, int out_size, void* d_ws, size_t ws_size,
                              hipStream_t stream) {
    const int N = in_sizes[0] / 3;
    const int E = in_sizes[1] / 2;
    const int L = in_sizes[9] / (64*64);
    const int NB = (N + (1<<BSHIFT) - 1) >> BSHIFT;   // buckets (<=256 for N<=131072)

    const float* x        = (const float*)d_in[0];
    const int*   edge     = (const int*)d_in[1];
    const int*   srcp     = edge;
    const int*   dstp     = edge + E;
    const int*   hb       = (const int*)d_in[2];
    const float* w_in     = (const float*)d_in[5];
    const float* a_src_in = (const float*)d_in[6];
    const float* a_dst_in = (const float*)d_in[7];
    const float* b_in     = (const float*)d_in[8];
    const float* w_l      = (const float*)d_in[9];
    const float* a_src_l  = (const float*)d_in[10];
    const float* a_dst_l  = (const float*)d_in[11];
    const float* b_l      = (const float*)d_in[12];
    const float* mlp_w1   = (const float*)d_in[13];
    const float* mlp_b1   = (const float*)d_in[14];
    const float* mlp_w2   = (const float*)d_in[15];
    const float* mlp_b2   = (const float*)d_in[16];
    const float* vn_emb   = (const float*)d_in[17];
    float*       out      = (float*)d_out;

    // ---- workspace carve (256B-aligned) ----
    char* ws = (char*)d_ws;
    size_t off = 0;
    auto carve = [&](size_t bytes) -> char* {
        char* p = ws + off;
        off = (off + bytes + 255) & ~(size_t)255;
        return p;
    };
    unsigned short* h = (unsigned short*)carve((size_t)N*64*2);  // bf16; aliased as pairs in CSR build
    float* outA   = (float*)carve((size_t)N*64*4);
    float* ssrc   = (float*)carve((size_t)N*4);
    float* sdst   = (float*)carve((size_t)N*4);
    int*   rowptr = (int*)carve((size_t)(N+1)*4);
    char*  zstart = ws + off;
    int*   bucketCount = (int*)carve(256*4);
    int*   hbBins = (int*)carve(256*4);
    size_t zbytes = (size_t)((ws + off) - zstart);
    int*   bucketOff = (int*)carve(257*4);
    int*   bucketCur = (int*)carve(256*4);
    int*   binptr = (int*)carve(257*4);
    int*   bincur = (int*)carve(256*4);
    int*   colarr = (int*)carve((size_t)E*4);
    int*   nodes  = (int*)carve((size_t)N*4);
    float* vseg   = (float*)carve((size_t)256*NSLICE*64*4);
    float* vw     = (float*)carve((size_t)257*64*4);
    if (off > ws_size) return;
    int2* pairs = (int2*)h;   // E*8 bytes <= N*128 bytes; pairs dead before h's first write

    // ---- CSR + node-bin build ----
    hipMemsetAsync(zstart, 0, zbytes, stream);
    const int nchunkE = (E + CHUNK - 1) / CHUNK;
    const int nchunkN = (N + CHUNK - 1) / CHUNK;
    k_bucket_count<<<nchunkE, 256, 0, stream>>>(dstp, E, NB, bucketCount);
    k_hb_count    <<<nchunkN, 256, 0, stream>>>(hb, N, hbBins);
    k_scan_all    <<<1, 256, 0, stream>>>(bucketCount, NB, E, N, bucketOff, bucketCur, rowptr,
                                          hbBins, binptr, bincur);
    k_bucket_place<<<nchunkE, 256, 0, stream>>>(srcp, dstp, E, NB, bucketCur, pairs);
    k_bucket_csr  <<<NB, 256, 0, stream>>>(pairs, bucketOff, N, rowptr, colarr);
    k_hb_place    <<<nchunkN, 256, 0, stream>>>(hb, N, bincur, nodes);

    const int nwb = (N + 3) / 4;     // wave-per-node kernels
    const int nmb = (N + 63) / 64;   // mfma transform blocks

    // ---- GAT layer 0 (IN -> H) ----
    k_transform_in<<<nwb, 256, 0, stream>>>(x, w_in, a_src_in, a_dst_in, h, ssrc, sdst, N);
    k_aggregate<<<nwb, 256, 0, stream>>>(h, ssrc, sdst, rowptr, colarr, b_in, outA, N);

    // ---- hidden layers ----
    for (int l = 0; l < L; ++l){
        const float* vnp = (l == 0) ? nullptr : vw;
        k_transform_h_mfma<<<nmb, 256, 0, stream>>>(outA, vnp, vn_emb, hb,
                                                    w_l + (size_t)l*4096,
                                                    a_src_l + (size_t)l*64,
                                                    a_dst_l + (size_t)l*64,
                                                    h, ssrc, sdst, N);
        const bool last = (l == L-1);
        float* dst_buf = last ? out : outA;
        k_aggregate<<<nwb, 256, 0, stream>>>(h, ssrc, sdst, rowptr, colarr,
                                             b_l + (size_t)l*64, dst_buf, N);
        if (!last){
            const float* vdo = (l == 0) ? nullptr : vw;
            const float* ro  = (l == 0) ? nullptr : (vw + 256*64);
            k_vn_segsum2<<<256*NSLICE, 256, 0, stream>>>(outA, nodes, binptr, vseg);
            k_vn_combine<<<1, 256, 0, stream>>>(vseg, vdo, ro, vn_emb, vw);
            k_vn_mlp<<<(257+3)/4, 256, 0, stream>>>(mlp_w1, mlp_b1, mlp_w2, mlp_b2, L, vw);
        }
    }
}